// Round 11
// baseline (589.929 us; speedup 1.0000x reference)
//
#include <hip/hip_runtime.h>
#include <math.h>

// ---- problem constants ----
static constexpr int B_  = 16;
static constexpr int N_  = 32;
static constexpr int E_  = 256;
static constexpr int D_  = 256;
static constexpr int H_  = 8;
static constexpr int HW_ = 784;
static constexpr int L_  = 4;
static constexpr int DH_ = 32;
static constexpr int FF_ = 1024;
static constexpr int BN_ = 512;
static constexpr int BE_ = 4096;
static constexpr int NE_ = 288;   // N+E
static constexpr int NC_ = 13;    // key chunks of 64 (784 -> 13)
static constexpr int NBLK_ = B_ * H_ * 9;   // 1152 attention blocks
#define SCALE_ 0.17677669529663687f

// per-layer transposed-weight block (bf16 elems)
static constexpr size_t LAYER_W = 1114112;  // 9*65536 + 2*262144
static constexpr size_t OFF_Q   = 0;
static constexpr size_t OFF_K   = 65536;    // K then V contiguous -> fused N=512 GEMM
static constexpr size_t OFF_WO  = 196608;
static constexpr size_t OFF_WN1 = 262144;   // WN1 then WN2 contiguous -> fused N=512 GEMM
static constexpr size_t OFF_WE  = 393216;
static constexpr size_t OFF_WEO = 458752;
static constexpr size_t OFF_WNO = 524288;
static constexpr size_t OFF_W1  = 589824;
static constexpr size_t OFF_W2  = 851968;

typedef __attribute__((ext_vector_type(8))) short bf16x8;
typedef __attribute__((ext_vector_type(4))) float f32x4;

typedef __attribute__((address_space(1))) const unsigned int gas_uint;
typedef __attribute__((address_space(3))) unsigned int las_uint;

__device__ __forceinline__ void gload16(const unsigned short* g, unsigned short* lds) {
    __builtin_amdgcn_global_load_lds((gas_uint*)g, (las_uint*)lds, 16, 0, 0);
}

__device__ __forceinline__ float gelu_f(float x) {
    return 0.5f * x * (1.0f + erff(x * 0.7071067811865476f));
}

__device__ __forceinline__ unsigned short f2bf(float x) {
    unsigned u = __float_as_uint(x);
    u += 0x7FFFu + ((u >> 16) & 1u);   // RNE
    return (unsigned short)(u >> 16);
}
__device__ __forceinline__ unsigned pack2bf(float a, float b) {
    return (unsigned)f2bf(a) | ((unsigned)f2bf(b) << 16);
}
__device__ __forceinline__ float bf2f(unsigned short u) {
    return __uint_as_float(((unsigned)u) << 16);
}

// ---------------- elementwise / LN kernels ----------------

__global__ void concat_kernel(const float* __restrict__ nodes, const float* __restrict__ edges,
                              float* __restrict__ ne) {
    int tid = blockIdx.x * 256 + threadIdx.x;   // B*NE*D
    int d = tid & 255;
    int row = tid >> 8;
    int b = row / NE_, pos = row % NE_;
    float v = (pos < N_) ? nodes[(size_t)(b * N_ + pos) * D_ + d]
                         : edges[(size_t)(b * E_ + (pos - N_)) * D_ + d];
    ne[tid] = v;
}

// images f32 -> bf16 (once per call)
__global__ void imgcast_kernel(const float* __restrict__ img, unsigned short* __restrict__ out) {
    int tid = blockIdx.x * 256 + threadIdx.x;   // (B*HW*D)/8 threads
    const float* p = img + (size_t)tid * 8;
    float4 a = *(const float4*)(p);
    float4 b = *(const float4*)(p + 4);
    uint4 o = make_uint4(pack2bf(a.x, a.y), pack2bf(a.z, a.w),
                         pack2bf(b.x, b.y), pack2bf(b.z, b.w));
    *(uint4*)&out[(size_t)tid * 8] = o;
}

// ---- zero init for mask flag ----
__global__ void zeroinit_kernel(int* maskflag) {
    if (threadIdx.x == 0 && blockIdx.x == 0) *maskflag = 0;
}

// ---- mask zero check: OR-reduce all bits; sets flag if any nonzero ----
__global__ __launch_bounds__(256) void maskchk_kernel(const float* __restrict__ mask,
                                                      int* __restrict__ flag) {
    const size_t total = (size_t)B_ * H_ * NE_ * HW_ / 4;   // uint4 count
    const uint4* m = (const uint4*)mask;
    unsigned acc = 0;
    for (size_t i = (size_t)blockIdx.x * 256 + threadIdx.x; i < total; i += (size_t)gridDim.x * 256) {
        uint4 v = m[i];
        acc |= v.x | v.y | v.z | v.w;
    }
    unsigned long long bal = __ballot(acc != 0);
    if (bal != 0 && (threadIdx.x & 63) == (__ffsll((long long)bal) - 1))
        atomicOr(flag, 1);
}

// ---- mask preprocessing: f32 [B,H,NE,HW] -> bf16 fragment layout ----
// gated: early-exit when mask is all zero (attn won't read pmask then)
__global__ __launch_bounds__(128) void premask_kernel(const float* __restrict__ mask,
                                                      unsigned short* __restrict__ pmask,
                                                      const int* __restrict__ flag) {
    if (*flag == 0) return;
    const int bid = blockIdx.x;          // bq*NC_ + c
    const int c = bid % NC_;
    const int bq = bid / NC_;
    const int h = bq & 7;
    const int qt = (bq >> 3) % 9;
    const int b = (bq >> 3) / 9;
    const int q0 = qt * 32, c0 = c * 64;
    __shared__ float ts[32][68];
    const int t = threadIdx.x;
    const int row = t >> 2, cg = (t & 3) * 16;
    const float* mrow = mask + ((size_t)(b * H_ + h) * NE_ + q0 + row) * (size_t)HW_;
    #pragma unroll
    for (int i = 0; i < 4; ++i) {
        int col = c0 + cg + i * 4;
        float4 m4;
        if (col + 4 <= HW_) {
            m4 = *(const float4*)(mrow + col);
        } else {
            m4.x = (col + 0 < HW_) ? mrow[col + 0] : -1e30f;
            m4.y = (col + 1 < HW_) ? mrow[col + 1] : -1e30f;
            m4.z = (col + 2 < HW_) ? mrow[col + 2] : -1e30f;
            m4.w = (col + 3 < HW_) ? mrow[col + 3] : -1e30f;
        }
        *(float4*)&ts[row][cg + i * 4] = m4;
    }
    __syncthreads();
    const int w = t >> 6, lg = (t & 63) >> 4, lr = t & 15;
    const int r0 = w * 16 + lg * 4;
    unsigned u[8];
    #pragma unroll
    for (int rg = 0; rg < 4; ++rg) {
        u[rg * 2 + 0] = pack2bf(ts[r0 + rg][0 * 16 + lr], ts[r0 + rg][1 * 16 + lr]);
        u[rg * 2 + 1] = pack2bf(ts[r0 + rg][2 * 16 + lr], ts[r0 + rg][3 * 16 + lr]);
    }
    uint4* dst = (uint4*)(pmask + (size_t)bid * 2048 + t * 16);
    dst[0] = make_uint4(u[0], u[1], u[2], u[3]);
    dst[1] = make_uint4(u[4], u[5], u[6], u[7]);
}

// LN core given the row value already in-register
__device__ __forceinline__ float ln_from_val(float v, int d,
                                             const float* __restrict__ g, const float* __restrict__ bta,
                                             float* sh1, float* sh2) {
    float s = v, s2 = v * v;
    #pragma unroll
    for (int o = 32; o >= 1; o >>= 1) { s += __shfl_down(s, o); s2 += __shfl_down(s2, o); }
    int lane = d & 63, w = d >> 6;
    if (lane == 0) { sh1[w] = s; sh2[w] = s2; }
    __syncthreads();
    if (d == 0) {
        float a = sh1[0] + sh1[1] + sh1[2] + sh1[3];
        float c = sh2[0] + sh2[1] + sh2[2] + sh2[3];
        sh1[0] = a; sh2[0] = c;
    }
    __syncthreads();
    float mean = sh1[0] * (1.0f / D_);
    float var  = sh2[0] * (1.0f / D_) - mean * mean;
    float rstd = rsqrtf(var + 1e-5f);
    return (v - mean) * rstd * g[d] + bta[d];
}

// LN -> bf16 out
__global__ __launch_bounds__(256) void ln_kernel(const float* __restrict__ x,
                                                 unsigned short* __restrict__ y,
                                                 const float* __restrict__ g,
                                                 const float* __restrict__ bta) {
    __shared__ float sh1[4], sh2[4];
    const int row = blockIdx.x, d = threadIdx.x;
    float v = x[(size_t)row * D_ + d];
    y[(size_t)row * D_ + d] = f2bf(ln_from_val(v, d, g, bta, sh1, sh2));
}

// LN2 fused with +enc and node/edge split, bf16 out
__global__ __launch_bounds__(256) void ln2enc_kernel(const float* __restrict__ x,
                                                     const float* __restrict__ g,
                                                     const float* __restrict__ bta,
                                                     const float* __restrict__ node_enc,
                                                     const float* __restrict__ edge_enc,
                                                     unsigned short* __restrict__ nodes_f,
                                                     unsigned short* __restrict__ edges_f) {
    __shared__ float sh1[4], sh2[4];
    const int row = blockIdx.x, d = threadIdx.x;
    float v = x[(size_t)row * D_ + d];
    float val = ln_from_val(v, d, g, bta, sh1, sh2);
    int b = row / NE_, pos = row % NE_;
    if (pos < N_) {
        int rn = b * N_ + pos;
        nodes_f[(size_t)rn * D_ + d] = f2bf(val + node_enc[(size_t)rn * D_ + d]);
    } else {
        int re = b * E_ + (pos - N_);
        edges_f[(size_t)re * D_ + d] = f2bf(val + edge_enc[(size_t)re * D_ + d]);
    }
}

// fused: node-rows aggregate CSR softmax inline; edge-rows read new_edges;
// then ne += ls2*gat and lnbuf = LN3(ne), bf16
__global__ __launch_bounds__(256) void gatagg_ln_kernel(
    const float* __restrict__ vals, const float* __restrict__ pres,
    const int* __restrict__ csr_off, const int* __restrict__ csr_perm,
    const float* __restrict__ new_edges, const float* __restrict__ ls2l,
    const float* __restrict__ g, const float* __restrict__ bta,
    float* __restrict__ ne, unsigned short* __restrict__ lnb) {
    __shared__ float sh1[4], sh2[4];
    __shared__ float sms[8], sden[8];
    const int row = blockIdx.x, d = threadIdx.x;
    int b = row / NE_, pos = row % NE_;
    float gv;
    if (pos < N_) {            // block-uniform branch
        int n = b * N_ + pos;
        int s = csr_off[n], e2 = csr_off[n + 1];
        if (d < 8) {
            float mx = -INFINITY;
            for (int i = s; i < e2; ++i) mx = fmaxf(mx, pres[csr_perm[i] * H_ + d]);
            float sum = 0.f;
            for (int i = s; i < e2; ++i) sum += __expf(pres[csr_perm[i] * H_ + d] - mx);
            sms[d] = mx; sden[d] = sum;
        }
        __syncthreads();
        int h = d >> 5;
        float ms = sms[h];
        float rd = 1.0f / sden[h];
        float acc = 0.f;
        for (int i = s; i < e2; ++i) {
            int e = csr_perm[i];
            acc += vals[(size_t)e * D_ + d] * (__expf(pres[e * H_ + h] - ms) * rd);
        }
        gv = acc;
    } else {
        gv = new_edges[(size_t)(b * E_ + (pos - N_)) * D_ + d];
    }
    float v = ne[(size_t)row * D_ + d] + ls2l[d] * gv;
    ne[(size_t)row * D_ + d] = v;
    lnb[(size_t)row * D_ + d] = f2bf(ln_from_val(v, d, g, bta, sh1, sh2));
}

// ---------------- weight transpose+cast: W[K,N] f32 -> Wt[N,K] bf16 ----------------
__global__ __launch_bounds__(256) void wtrans_kernel(
    const float* __restrict__ Wqkv, const float* __restrict__ Wo,
    const float* __restrict__ Wn1,  const float* __restrict__ Wn2,
    const float* __restrict__ We,   const float* __restrict__ Weo,
    const float* __restrict__ Wno,  const float* __restrict__ W1,
    const float* __restrict__ W2,   unsigned short* __restrict__ wT)
{
    const int bid = blockIdx.x;
    const int l = bid / 1088;
    int tl = bid % 1088;
    const float* src; int ld, K, Nn; unsigned short* dst;
    if (tl < 576) {
        int mid = tl >> 6; tl &= 63;
        K = 256; Nn = 256;
        if (mid < 3) {
            src = Wqkv + (size_t)l * 256 * 768 + mid * 256; ld = 768;
            dst = wT + (size_t)l * LAYER_W + (size_t)mid * 65536;
        } else {
            const float* bases[6] = {Wo, Wn1, Wn2, We, Weo, Wno};
            src = bases[mid - 3] + (size_t)l * 65536; ld = 256;
            dst = wT + (size_t)l * LAYER_W + OFF_WO + (size_t)(mid - 3) * 65536;
        }
    } else if (tl < 832) {
        tl -= 576; K = 256; Nn = 1024;
        src = W1 + (size_t)l * 262144; ld = 1024;
        dst = wT + (size_t)l * LAYER_W + OFF_W1;
    } else {
        tl -= 832; K = 1024; Nn = 256;
        src = W2 + (size_t)l * 262144; ld = 256;
        dst = wT + (size_t)l * LAYER_W + OFF_W2;
    }
    const int ntn = Nn >> 5;
    const int k0 = (tl / ntn) << 5, n0 = (tl % ntn) << 5;
    __shared__ float ts[32][33];
    const int t = threadIdx.x;
    const int kl = t >> 5, nl = t & 31;
    #pragma unroll
    for (int rr = 0; rr < 4; ++rr)
        ts[kl + rr * 8][nl] = src[(size_t)(k0 + kl + rr * 8) * ld + n0 + nl];
    __syncthreads();
    const int onl = t >> 3, okl = (t & 7) << 2;
    ushort4 o;
    o.x = f2bf(ts[okl + 0][onl]); o.y = f2bf(ts[okl + 1][onl]);
    o.z = f2bf(ts[okl + 2][onl]); o.w = f2bf(ts[okl + 3][onl]);
    *(ushort4*)&dst[(size_t)(n0 + onl) * K + k0 + okl] = o;
}

// ---------------- 64-tile MFMA GEMM ----------------
// Linear LDS [64][64] with XOR swizzle: swizzled col (halves) = col ^ ((row&7)<<3).

struct GArgs {
    const unsigned short* A;
    const unsigned short* Bt;
    const float* bias;
    const float* bias2;
    void* C;
    int lda, ldc, K, outbf, nbx;
};

template<int MODE, int OUTBF>
__global__ __launch_bounds__(256) void mgemm_kernel(
    const unsigned short* __restrict__ A, int lda,
    const unsigned short* __restrict__ Bt,
    const float* __restrict__ bias,
    const float* __restrict__ bias2,
    const float* __restrict__ res,
    const float* __restrict__ ls,
    void* __restrict__ Cv, int ldc, int K)
{
    __shared__ __align__(16) unsigned short As[64 * 64];
    __shared__ __align__(16) unsigned short Bs[64 * 64];
    const int m0 = blockIdx.y * 64, n0 = blockIdx.x * 64;
    const int t = threadIdx.x;
    const int l = t & 63, w = t >> 6;
    const int wr = (w >> 1) * 32, wc = (w & 1) * 32;
    const int frow = l & 15, kg = l >> 4;
    const int srow = w * 8 + (l >> 3);
    const int scolh = 8 * ((l & 7) ^ (l >> 3));
    const int ldsoff = w * 512;
    const int sw = (frow & 7) << 3;
    f32x4 acc[2][2];
    acc[0][0] = (f32x4){0.f,0.f,0.f,0.f}; acc[0][1] = acc[0][0];
    acc[1][0] = acc[0][0];                acc[1][1] = acc[0][0];
    for (int k0 = 0; k0 < K; k0 += 64) {
        const unsigned short* ga = A  + (size_t)(m0 + srow) * lda + k0 + scolh;
        const unsigned short* gb = Bt + (size_t)(n0 + srow) * K   + k0 + scolh;
        gload16(ga,                As + ldsoff);
        gload16(ga + 32 * lda,     As + ldsoff + 2048);
        gload16(gb,                Bs + ldsoff);
        gload16(gb + (size_t)32 * K, Bs + ldsoff + 2048);
        __syncthreads();
        #pragma unroll
        for (int kk = 0; kk < 2; ++kk) {
            const int off = (kk * 32 + kg * 8) ^ sw;
            bf16x8 af0 = *(const bf16x8*)&As[(wr + frow) * 64 + off];
            bf16x8 af1 = *(const bf16x8*)&As[(wr + 16 + frow) * 64 + off];
            bf16x8 bf0 = *(const bf16x8*)&Bs[(wc + frow) * 64 + off];
            bf16x8 bf1 = *(const bf16x8*)&Bs[(wc + 16 + frow) * 64 + off];
            acc[0][0] = __builtin_amdgcn_mfma_f32_16x16x32_bf16(af0, bf0, acc[0][0], 0, 0, 0);
            acc[0][1] = __builtin_amdgcn_mfma_f32_16x16x32_bf16(af0, bf1, acc[0][1], 0, 0, 0);
            acc[1][0] = __builtin_amdgcn_mfma_f32_16x16x32_bf16(af1, bf0, acc[1][0], 0, 0, 0);
            acc[1][1] = __builtin_amdgcn_mfma_f32_16x16x32_bf16(af1, bf1, acc[1][1], 0, 0, 0);
        }
        __syncthreads();
    }
    #pragma unroll
    for (int fr = 0; fr < 2; ++fr) {
        #pragma unroll
        for (int fc = 0; fc < 2; ++fc) {
            int n = n0 + wc + fc * 16 + frow;
            float bv = (bias2 != nullptr && n >= 256) ? bias2[n - 256] : bias[n];
            float lv = (MODE == 2) ? ls[n] : 0.f;
            #pragma unroll
            for (int rg = 0; rg < 4; ++rg) {
                int m = m0 + wr + fr * 16 + kg * 4 + rg;
                float vv = acc[fr][fc][rg] + bv;
                if (MODE == 1) vv = gelu_f(vv);
                if (MODE == 2) vv = res[(size_t)m * ldc + n] + lv * vv;
                if (OUTBF) ((unsigned short*)Cv)[(size_t)m * ldc + n] = f2bf(vv);
                else       ((float*)Cv)[(size_t)m * ldc + n] = vv;
            }
        }
    }
}

// WEO GEMM with fused vin epilogue:
//   new_edges[m][n] = acc + beo[n]            (f32, for gatagg)
//   vin[m][n]       = bf16(nodes_f[idx1[m]][n] + new_edges[m][n])
__global__ __launch_bounds__(256) void mgemm_weo_kernel(
    const unsigned short* __restrict__ A,
    const unsigned short* __restrict__ Bt,
    const float* __restrict__ bias,
    const unsigned short* __restrict__ nodes_f,
    const int* __restrict__ idx1,
    float* __restrict__ new_edges,
    unsigned short* __restrict__ vin)
{
    __shared__ __align__(16) unsigned short As[64 * 64];
    __shared__ __align__(16) unsigned short Bs[64 * 64];
    const int m0 = blockIdx.y * 64, n0 = blockIdx.x * 64;
    const int t = threadIdx.x;
    const int l = t & 63, w = t >> 6;
    const int wr = (w >> 1) * 32, wc = (w & 1) * 32;
    const int frow = l & 15, kg = l >> 4;
    const int srow = w * 8 + (l >> 3);
    const int scolh = 8 * ((l & 7) ^ (l >> 3));
    const int ldsoff = w * 512;
    const int sw = (frow & 7) << 3;
    f32x4 acc[2][2];
    acc[0][0] = (f32x4){0.f,0.f,0.f,0.f}; acc[0][1] = acc[0][0];
    acc[1][0] = acc[0][0];                acc[1][1] = acc[0][0];
    for (int k0 = 0; k0 < 256; k0 += 64) {
        const unsigned short* ga = A  + (size_t)(m0 + srow) * 256 + k0 + scolh;
        const unsigned short* gb = Bt + (size_t)(n0 + srow) * 256 + k0 + scolh;
        gload16(ga,                 As + ldsoff);
        gload16(ga + 32 * 256,      As + ldsoff + 2048);
        gload16(gb,                 Bs + ldsoff);
        gload16(gb + 32 * 256,      Bs + ldsoff + 2048);
        __syncthreads();
        #pragma unroll
        for (int kk = 0; kk < 2; ++kk) {
            const int off = (kk * 32 + kg * 8) ^ sw;
            bf16x8 af0 = *(const bf16x8*)&As[(wr + frow) * 64 + off];
            bf16x8 af1 = *(const bf16x8*)&As[(wr + 16 + frow) * 64 + off];
            bf16x8 bf0 = *(const bf16x8*)&Bs[(wc + frow) * 64 + off];
            bf16x8 bf1 = *(const bf16x8*)&Bs[(wc + 16 + frow) * 64 + off];
            acc[0][0] = __builtin_amdgcn_mfma_f32_16x16x32_bf16(af0, bf0, acc[0][0], 0, 0, 0);
            acc[0][1] = __builtin_amdgcn_mfma_f32_16x16x32_bf16(af0, bf1, acc[0][1], 0, 0, 0);
            acc[1][0] = __builtin_amdgcn_mfma_f32_16x16x32_bf16(af1, bf0, acc[1][0], 0, 0, 0);
            acc[1][1] = __builtin_amdgcn_mfma_f32_16x16x32_bf16(af1, bf1, acc[1][1], 0, 0, 0);
        }
        __syncthreads();
    }
    #pragma unroll
    for (int fr = 0; fr < 2; ++fr) {
        #pragma unroll
        for (int rg = 0; rg < 4; ++rg) {
            int m = m0 + wr + fr * 16 + kg * 4 + rg;
            int src = idx1[m];
            #pragma unroll
            for (int fc = 0; fc < 2; ++fc) {
                int n = n0 + wc + fc * 16 + frow;
                float vv = acc[fr][fc][rg] + bias[n];
                new_edges[(size_t)m * 256 + n] = vv;
                vin[(size_t)m * 256 + n] = f2bf(bf2f(nodes_f[(size_t)src * 256 + n]) + vv);
            }
        }
    }
}

// dual-descriptor GEMM: two independent MODE-0 GEMMs in one dispatch
__global__ __launch_bounds__(256) void mgemm2_kernel(GArgs g0, GArgs g1, int nblk0) {
    const bool first = (int)blockIdx.x < nblk0;
    GArgs g = first ? g0 : g1;
    const int bid = first ? blockIdx.x : blockIdx.x - nblk0;
    __shared__ __align__(16) unsigned short As[64 * 64];
    __shared__ __align__(16) unsigned short Bs[64 * 64];
    const int m0 = (bid / g.nbx) * 64, n0 = (bid % g.nbx) * 64;
    const int t = threadIdx.x;
    const int l = t & 63, w = t >> 6;
    const int wr = (w >> 1) * 32, wc = (w & 1) * 32;
    const int frow = l & 15, kg = l >> 4;
    const int srow = w * 8 + (l >> 3);
    const int scolh = 8 * ((l & 7) ^ (l >> 3));
    const int ldsoff = w * 512;
    const int sw = (frow & 7) << 3;
    f32x4 acc[2][2];
    acc[0][0] = (f32x4){0.f,0.f,0.f,0.f}; acc[0][1] = acc[0][0];
    acc[1][0] = acc[0][0];                acc[1][1] = acc[0][0];
    for (int k0 = 0; k0 < g.K; k0 += 64) {
        const unsigned short* ga = g.A  + (size_t)(m0 + srow) * g.lda + k0 + scolh;
        const unsigned short* gb = g.Bt + (size_t)(n0 + srow) * g.K   + k0 + scolh;
        gload16(ga,                  As + ldsoff);
        gload16(ga + 32 * g.lda,     As + ldsoff + 2048);
        gload16(gb,                  Bs + ldsoff);
        gload16(gb + (size_t)32 * g.K, Bs + ldsoff + 2048);
        __syncthreads();
        #pragma unroll
        for (int kk = 0; kk < 2; ++kk) {
            const int off = (kk * 32 + kg * 8) ^ sw;
            bf16x8 af0 = *(const bf16x8*)&As[(wr + frow) * 64 + off];
            bf16x8 af1 = *(const bf16x8*)&As[(wr + 16 + frow) * 64 + off];
            bf16x8 bf0 = *(const bf16x8*)&Bs[(wc + frow) * 64 + off];
            bf16x8 bf1 = *(const bf16x8*)&Bs[(wc + 16 + frow) * 64 + off];
            acc[0][0] = __builtin_amdgcn_mfma_f32_16x16x32_bf16(af0, bf0, acc[0][0], 0, 0, 0);
            acc[0][1] = __builtin_amdgcn_mfma_f32_16x16x32_bf16(af0, bf1, acc[0][1], 0, 0, 0);
            acc[1][0] = __builtin_amdgcn_mfma_f32_16x16x32_bf16(af1, bf0, acc[1][0], 0, 0, 0);
            acc[1][1] = __builtin_amdgcn_mfma_f32_16x16x32_bf16(af1, bf1, acc[1][1], 0, 0, 0);
        }
        __syncthreads();
    }
    #pragma unroll
    for (int fr = 0; fr < 2; ++fr) {
        #pragma unroll
        for (int fc = 0; fc < 2; ++fc) {
            int n = n0 + wc + fc * 16 + frow;
            float bv = (g.bias2 != nullptr && n >= 256) ? g.bias2[n - 256] : g.bias[n];
            #pragma unroll
            for (int rg = 0; rg < 4; ++rg) {
                int m = m0 + wr + fr * 16 + kg * 4 + rg;
                float vv = acc[fr][fc][rg] + bv;
                if (g.outbf) ((unsigned short*)g.C)[(size_t)m * g.ldc + n] = f2bf(vv);
                else         ((float*)g.C)[(size_t)m * g.ldc + n] = vv;
            }
        }
    }
}

// ---------------- 128-tile MFMA GEMM (big GEMMs): BM=BN=128, BK=64 ----------------
// MODE 0: +bias ; MODE 1: gelu(+bias). bf16 output.
template<int MODE>
__global__ __launch_bounds__(256) void mgemm128_kernel(
    const unsigned short* __restrict__ A, int lda,
    const unsigned short* __restrict__ Bt,
    const float* __restrict__ bias,
    unsigned short* __restrict__ C, int ldc, int K, int nbx)
{
    __shared__ __align__(16) unsigned short As[128 * 64];
    __shared__ __align__(16) unsigned short Bs[128 * 64];
    const int bid = blockIdx.x;
    const int m0 = (bid / nbx) * 128, n0 = (bid % nbx) * 128;
    const int t = threadIdx.x;
    const int l = t & 63, w = t >> 6;
    const int wr = (w >> 1) * 64, wc = (w & 1) * 64;
    const int frow = l & 15, kg = l >> 4;
    const int srow = w * 8 + (l >> 3);
    const int scolh = 8 * ((l & 7) ^ (l >> 3));
    const int ldsoff = w * 512;
    const int sw = (frow & 7) << 3;
    f32x4 acc[4][4];
    #pragma unroll
    for (int i = 0; i < 4; ++i)
        #pragma unroll
        for (int j = 0; j < 4; ++j) acc[i][j] = (f32x4){0.f, 0.f, 0.f, 0.f};
    for (int k0 = 0; k0 < K; k0 += 64) {
        #pragma unroll
        for (int j = 0; j < 4; ++j) {
            gload16(A  + (size_t)(m0 + j * 32 + srow) * lda + k0 + scolh, As + j * 2048 + ldsoff);
            gload16(Bt + (size_t)(n0 + j * 32 + srow) * K   + k0 + scolh, Bs + j * 2048 + ldsoff);
        }
        __syncthreads();
        #pragma unroll
        for (int kk = 0; kk < 2; ++kk) {
            const int off = (kk * 32 + kg * 8) ^ sw;
            bf16x8 af[4], bf[4];
            #pragma unroll
            for (int i = 0; i < 4; ++i) {
                af[i] = *(const bf16x8*)&As[(wr + i * 16 + frow) * 64 + off];
                bf[i] = *(const bf16x8*)&Bs[(wc + i * 16 + frow) * 64 + off];
            }
            #pragma unroll
            for (int i = 0; i < 4; ++i)
                #pragma unroll
                for (int j = 0; j < 4; ++j)
                    acc[i][j] = __builtin_amdgcn_mfma_f32_16x16x32_bf16(af[i], bf[j], acc[i][j], 0, 0, 0);
        }
        __syncthreads();
    }
    #pragma unroll
    for (int fr = 0; fr < 4; ++fr) {
        #pragma unroll
        for (int fc = 0; fc < 4; ++fc) {
            int n = n0 + wc + fc * 16 + frow;
            float bv = bias[n];
            #pragma unroll
            for (int rg = 0; rg < 4; ++rg) {
                int m = m0 + wr + fr * 16 + kg * 4 + rg;
                float vv = acc[fr][fc][rg] + bv;
                if (MODE == 1) vv = gelu_f(vv);
                C[(size_t)m * ldc + n] = f2bf(vv);
            }
        }
    }
}

// ---------------- MFMA flash attention (flag-gated bf16 mask) ----------------
// 1152 blocks x 128 threads. Block = one (b,h) x 32 q-rows (2 waves x 16 rows).
// kv layout: [B*HW][512] bf16, cols 0-255 = K, 256-511 = V (head h at h*32).
// maskflag==0 -> fixed-max softmax (scores provably small), no max tracking.
__global__ __launch_bounds__(128) void attn_kernel(
    const unsigned short* __restrict__ q, const unsigned short* __restrict__ kv,
    const unsigned short* __restrict__ pmask, const int* __restrict__ maskflag,
    unsigned short* __restrict__ ctx)
{
    const int bid = blockIdx.x;
    const int h = bid & 7;
    const int qt = (bid >> 3) % 9;
    const int b = (bid >> 3) / 9;
    const int q0 = qt * 32;
    const int t = threadIdx.x;
    const int w = t >> 6, l = t & 63;
    const int lr = l & 15, lg = l >> 4;
    const int hasmask = *maskflag;

    __shared__ unsigned short Ks[2][64][40];
    __shared__ unsigned short Vs[2][32][72];
    __shared__ unsigned short Pl[2][16][72];

    bf16x8 qfrag = *(const bf16x8*)(q + ((size_t)(b * NE_ + q0 + w * 16 + lr)) * D_ + h * DH_ + lg * 8);

    // staging assignment
    const int kkey = t >> 1, kdh = (t & 1) * 16;          // K: 1 key, 16 dh
    const int vdh = (t & 7) * 4, vk0 = (t >> 3) * 2;      // V: key pairs, 4 dh
    const unsigned short* kbase = kv + ((size_t)b * HW_) * 512 + h * DH_;
    const unsigned short* vbase = kv + ((size_t)b * HW_) * 512 + 256 + h * DH_;
    const uint4* mbase = (const uint4*)(pmask + (size_t)bid * NC_ * 2048 + t * 16);

    uint4 kq0, kq1;
    ushort4 va[2], vb4[2];
    uint4 mc0 = make_uint4(0,0,0,0), mc1 = mc0, mn0 = mc0, mn1 = mc0;

    auto issue_kv = [&](int c0) {
        {
            int key = c0 + kkey;
            bool ok = key < HW_;
            const unsigned short* kp = kbase + (size_t)(ok ? key : 0) * 512 + kdh;
            kq0 = *(const uint4*)(kp);
            kq1 = *(const uint4*)(kp + 8);
            if (!ok) { kq0 = make_uint4(0,0,0,0); kq1 = kq0; }
        }
        #pragma unroll
        for (int r = 0; r < 2; ++r) {
            int key = c0 + vk0 + 32 * r;
            bool ok0 = key < HW_, ok1 = (key + 1) < HW_;
            const unsigned short* vp = vbase + (size_t)(ok0 ? key : 0) * 512 + vdh;
            va[r]  = *(const ushort4*)(vp);
            vb4[r] = *(const ushort4*)(vp + (ok1 ? 512 : 0));
            if (!ok0) va[r]  = make_ushort4(0,0,0,0);
            if (!ok1) vb4[r] = make_ushort4(0,0,0,0);
        }
    };
    auto write_kv = [&](int bufi) {
        *(uint4*)&Ks[bufi][kkey][kdh]     = kq0;
        *(uint4*)&Ks[bufi][kkey][kdh + 8] = kq1;
        #pragma unroll
        for (int r = 0; r < 2; ++r) {
            const unsigned short* a = (const unsigned short*)&va[r];
            const unsigned short* c = (const unsigned short*)&vb4[r];
            #pragma unroll
            for (int i = 0; i < 4; ++i)
                *(unsigned*)&Vs[bufi][vdh + i][vk0 + 32 * r] = (unsigned)a[i] | ((unsigned)c[i] << 16);
        }
    };

    f32x4 oacc[2];
    oacc[0] = (f32x4){0.f, 0.f, 0.f, 0.f}; oacc[1] = oacc[0];
    float m_i[4] = {-INFINITY, -INFINITY, -INFINITY, -INFINITY};
    float l_i[4] = {0.f, 0.f, 0.f, 0.f};

    issue_kv(0);
    if (hasmask) { mc0 = mbase[0]; mc1 = mbase[1]; }
    write_kv(0);
    if (hasmask) { mn0 = mbase[128]; mn1 = mbase[129]; }
    __syncthreads();

    for (int c = 0; c < NC_; ++c) {
        const int c0 = c * 64;
        const int cb = c & 1, nb = cb ^ 1;
        if (c + 1 < NC_) issue_kv(c0 + 64);

        // QK^T: S[16 q, 64 keys]
        f32x4 sacc[4];
        #pragma unroll
        for (int fc = 0; fc < 4; ++fc) {
            sacc[fc] = (f32x4){0.f, 0.f, 0.f, 0.f};
            bf16x8 kf = *(const bf16x8*)&Ks[cb][fc * 16 + lr][lg * 8];
            sacc[fc] = __builtin_amdgcn_mfma_f32_16x16x32_bf16(qfrag, kf, sacc[fc], 0, 0, 0);
        }
        float s[4][4];   // [fc][rg]
        if (hasmask) {
            unsigned uw[8] = {mc0.x, mc0.y, mc0.z, mc0.w, mc1.x, mc1.y, mc1.z, mc1.w};
            #pragma unroll
            for (int rg = 0; rg < 4; ++rg) {
                s[0][rg] = sacc[0][rg] * SCALE_ + bf2f((unsigned short)(uw[rg * 2] & 0xffff));
                s[1][rg] = sacc[1][rg] * SCALE_ + bf2f((unsigned short)(uw[rg * 2] >> 16));
                s[2][rg] = sacc[2][rg] * SCALE_ + bf2f((unsigned short)(uw[rg * 2 + 1] & 0xffff));
                s[3][rg] = sacc[3][rg] * SCALE_ + bf2f((unsigned short)(uw[rg * 2 + 1] >> 16));
            }
            // full online softmax
            float mloc[4];
            #pragma unroll
            for (int rg = 0; rg < 4; ++rg)
                mloc[rg] = fmaxf(fmaxf(s[0][rg], s[1][rg]), fmaxf(s[2][rg], s[3][rg]));
            #pragma unroll
            for (int off = 1; off < 16; off <<= 1)
                #pragma unroll
                for (int rg = 0; rg < 4; ++rg)
                    mloc[rg] = fmaxf(mloc[rg], __shfl_xor(mloc[rg], off));
            float scl[4], lloc[4];
            #pragma unroll
            for (int rg = 0; rg < 4; ++rg) {
                float mn = fmaxf(m_i[rg], mloc[rg]);
                scl[rg] = __expf(m_i[rg] - mn);
                m_i[rg] = mn;
            }
            #pragma unroll
            for (int rg = 0; rg < 4; ++rg) {
                float acc = 0.f;
                #pragma unroll
                for (int fc = 0; fc < 4; ++fc) {
                    float p = __expf(s[fc][rg] - m_i[rg]);
                    s[fc][rg] = p;
                    acc += p;
                }
                lloc[rg] = acc;
            }
            #pragma unroll
            for (int off = 1; off < 16; off <<= 1)
                #pragma unroll
                for (int rg = 0; rg < 4; ++rg)
                    lloc[rg] += __shfl_xor(lloc[rg], off);
            #pragma unroll
            for (int rg = 0; rg < 4; ++rg) {
                l_i[rg] = l_i[rg] * scl[rg] + lloc[rg];
                oacc[0][rg] *= scl[rg];
                oacc[1][rg] *= scl[rg];
            }
        } else {
            // fixed-max softmax: scores bounded (|s| << 88), no max tracking
            const bool tailc = (c == NC_ - 1);
            float lloc[4] = {0.f, 0.f, 0.f, 0.f};
            #pragma unroll
            for (int fc = 0; fc < 4; ++fc) {
                float pad = (tailc && (c0 + fc * 16 + lr) >= HW_) ? -1e30f : 0.f;
                #pragma unroll
                for (int rg = 0; rg < 4; ++rg) {
                    float p = __expf(sacc[fc][rg] * SCALE_ + pad);
                    s[fc][rg] = p;
                    lloc[rg] += p;
                }
            }
            #pragma unroll
            for (int off = 1; off < 16; off <<= 1)
                #pragma unroll
                for (int rg = 0; rg < 4; ++rg)
                    lloc[rg] += __shfl_xor(lloc[rg], off);
            #pragma unroll
            for (int rg = 0; rg < 4; ++rg)
                l_i[rg] += lloc[rg];
        }

        // P -> LDS (wave-private), then PV
        #pragma unroll
        for (int fc = 0; fc < 4; ++fc)
            #pragma unroll
            for (int rg = 0; rg < 4; ++rg)
                Pl[w][lg * 4 + rg][fc * 16 + lr] = f2bf(s[fc][rg]);
        #pragma unroll
        for (int ks2 = 0; ks2 < 2; ++ks2) {
            bf16x8 pf = *(const bf16x8*)&Pl[w][lr][ks2 * 32 + lg * 8];
            #pragma unroll
            for (int d2 = 0; d2 < 2; ++d2) {
                bf16x8 vf = *(const bf16x8*)&Vs[cb][d2 * 16 + lr][ks2 * 32 + lg * 8];
                oacc[d2] = __builtin_amdgcn_mfma_f32_16x16x32_bf16(pf, vf, oacc[d2], 0, 0, 0);
            }
        }

        if (hasmask) {
            mc0 = mn0; mc1 = mn1;
            if (c + 2 < NC_) {
                mn0 = mbase[(c + 2) * 128];
                mn1 = mbase[(c + 2) * 128 + 1];
            }
        }
        if (c + 1 < NC_) {
            write_kv(nb);
            __syncthreads();
        }
    }

    unsigned short* cbase = ctx + ((size_t)(b * NE_ + q0 + w * 16 + lg * 4)) * D_ + h * DH_;
    #pragma unroll
    for (int rg = 0; rg < 4; ++rg) {
        float inv = 1.0f / l_i[rg];
        #pragma unroll
        for (int d2 = 0; d2 < 2; ++d2)
            cbase[(size_t)rg * D_ + d2 * 16 + lr] = f2bf(oacc[d2][rg] * inv);
    }
}

// ---------------- GAT kernels ----------------

__global__ __launch_bounds__(256) void hidden_kernel(
    const float* __restrict__ gn12,
    unsigned short* __restrict__ hid, const int* __restrict__ idx0,
    const float* __restrict__ attn_p_l, float* __restrict__ pres) {
    int e = blockIdx.x;
    int d = threadIdx.x;
    int n = idx0[e];
    float x = bf2f(hid[(size_t)e * D_ + d]) + gn12[(size_t)n * 512 + d] + gn12[(size_t)n * 512 + 256 + d];
    float hv = gelu_f(x);
    hid[(size_t)e * D_ + d] = f2bf(hv);
    float pr = hv * attn_p_l[d];
    #pragma unroll
    for (int o = 1; o < 32; o <<= 1) pr += __shfl_xor(pr, o);
    if ((d & 31) == 0) pres[e * H_ + (d >> 5)] = pr;
}

// ---------------- CSR build (deterministic) ----------------

// merged count + scan in a single 512-thread block (LDS atomics; integer sum deterministic)
__global__ __launch_bounds__(512) void csr_build_kernel(const int* __restrict__ idx0,
                                                        int* __restrict__ csr_off) {
    __shared__ int cnt[BN_];
    __shared__ int buf[BN_];
    int t = threadIdx.x;
    cnt[t] = 0;
    __syncthreads();
    #pragma unroll
    for (int i = 0; i < BE_ / 512; ++i)
        atomicAdd(&cnt[idx0[t + i * 512]], 1);
    __syncthreads();
    int c = cnt[t];
    buf[t] = c;
    __syncthreads();
    for (int o = 1; o < BN_; o <<= 1) {
        int add = (t >= o) ? buf[t - o] : 0;
        __syncthreads();
        buf[t] += add;
        __syncthreads();
    }
    csr_off[t] = buf[t] - c;
    if (t == BN_ - 1) csr_off[BN_] = buf[t];
}

__global__ __launch_bounds__(64) void csr_fill(const int* __restrict__ idx0,
                                               const int* __restrict__ csr_off,
                                               int* __restrict__ csr_perm) {
    int n = blockIdx.x;
    int lane = threadIdx.x;
    int w = csr_off[n];
    for (int c0 = 0; c0 < BE_; c0 += 64) {
        int e = c0 + lane;
        bool m = (idx0[e] == n);
        unsigned long long bal = __ballot(m);
        if (m) {
            int pre = __popcll(bal & ((1ull << lane) - 1ull));
            csr_perm[w + pre] = e;
        }
        w += __popcll(bal);
    }
}

// ---------------- host orchestration ----------------

static void launch_mgemm(hipStream_t s, int mode, int outbf,
                         const unsigned short* A, int lda, const unsigned short* Bt,
                         const float* bias, const float* bias2, const float* res, const float* ls,
                         void* C, int ldc, int M, int N, int K) {
    dim3 g(N / 64, M / 64);
    if (mode == 0) {
        if (outbf) mgemm_kernel<0,1><<<g, 256, 0, s>>>(A, lda, Bt, bias, bias2, res, ls, C, ldc, K);
        else       mgemm_kernel<0,0><<<g, 256, 0, s>>>(A, lda, Bt, bias, bias2, res, ls, C, ldc, K);
    } else if (mode == 1) {
        mgemm_kernel<1,1><<<g, 256, 0, s>>>(A, lda, Bt, bias, bias2, res, ls, C, ldc, K);
    } else {
        mgemm_kernel<2,0><<<g, 256, 0, s>>>(A, lda, Bt, bias, bias2, res, ls, C, ldc, K);
    }
}

extern "C" void kernel_launch(void* const* d_in, const int* in_sizes, int n_in,
                              void* d_out, int out_size, void* d_ws, size_t ws_size,
                              hipStream_t stream) {
    const float* nodes    = (const float*)d_in[0];
    const float* edges    = (const float*)d_in[1];
    const float* images   = (const float*)d_in[2];
    const float* mask     = (const float*)d_in[3];
    const float* node_enc = (const float*)d_in[4];
    const float* edge_enc = (const float*)d_in[5];
    const float* ln1_g = (const float*)d_in[6];
    const float* ln1_b = (const float*)d_in[7];
    const float* Wqkv  = (const float*)d_in[8];
    const float* bqkv  = (const float*)d_in[9];
    const float* Wo    = (const float*)d_in[10];
    const float* bo    = (const float*)d_in[11];
    const float* ls1   = (const float*)d_in[12];
    const float* ln2_g = (const float*)d_in[13];
    const float* ln2_b = (const float*)d_in[14];
    const float* Wn1   = (const float*)d_in[15];
    const float* bn1   = (const float*)d_in[16];
    const float* Wn2   = (const float*)d_in[17];
    const float* bn2   = (const float*)d_in[18];
    const float* We    = (const float*)d_in[19];
    const float* be    = (const float*)d_in[20];
    const float* attn_p= (const float*)d_in[21];
    const float* Weo   = (const float*)d_in[22];
    const float* beo   = (const float*)d_in[23];
    const float* Wno   = (const float*)d_in[24];
    const float* bno   = (const float*)d_in[25];
    const float* ls2   = (const float*)d_in[26];
    const float* ln3_g = (const float*)d_in[27];
    const float* ln3_b = (const float*)d_in[28];
    const float* W1    = (const float*)d_in[29];
    const float* b1    = (const float*)d_in[30];
    const float* W2    = (const float*)d_in[31];
    const float* b2    = (const float*)d_in[32];
    const float* ls3   = (const float*)d_in[33];
    const int*   edge_index = (const int*)d_in[34];
    const int* idx0 = edge_index;
    const int* idx1 = edge_index + BE_;

    float* ne = (float*)d_out;   // d_out doubles as the running `ne` buffer

    float* cur = (float*)d_ws;
    auto alloc = [&](size_t nfl) { float* p = cur; cur += nfl; return p; };
    auto allocbf = [&](size_t nbf) { float* p = cur; cur += (nbf + 1) / 2; return (unsigned short*)p; };

    unsigned short* lnbuf   = allocbf((size_t)B_ * NE_ * D_);
    unsigned short* qb      = allocbf((size_t)B_ * NE_ * D_);
    unsigned short* kvb     = allocbf((size_t)B_ * HW_ * 512);     // K|V fused, ld=512
    unsigned short* ffnh    = kvb;   // alias: kv dead by FFN time
    unsigned short* imgbf   = allocbf((size_t)B_ * HW_ * D_);
    unsigned short* ctxb    = allocbf((size_t)B_ * NE_ * D_);
    unsigned short* nodes_f = allocbf((size_t)BN_ * D_);
    unsigned short* edges_f = allocbf((size_t)BE_ * D_);
    unsigned short* hid     = allocbf((size_t)BE_ * D_);
    unsigned short* vin     = allocbf((size_t)BE_ * D_);
    unsigned short* pmaskb  = allocbf((size_t)NBLK_ * NC_ * 2048); // fragment-layout bf16 mask
    float* gn12     = alloc((size_t)BN_ * 512);
    float* pres     = alloc((size_t)BE_ * H_);
    float* new_edges= alloc((size_t)BE_ * D_);
    float* valsb    = alloc((size_t)BE_ * D_);
    int* csr_off  = (int*)cur; cur += BN_ + 4;
    int* csr_perm = (int*)cur; cur += BE_;
    int* maskflag = (int*)cur; cur += 4;
    cur = (float*)(((uintptr_t)cur + 255) & ~(uintptr_t)255);
    unsigned short* wT = (unsigned short*)cur;   // 4 * LAYER_W bf16

    // ---- once-per-call preprocessing ----
    zeroinit_kernel<<<1, 64, 0, stream>>>(maskflag);
    maskchk_kernel<<<2048, 256, 0, stream>>>(mask, maskflag);
    wtrans_kernel<<<4 * 1088, 256, 0, stream>>>(Wqkv, Wo, Wn1, Wn2, We, Weo, Wno, W1, W2, wT);
    imgcast_kernel<<<(B_ * HW_ * D_) / (256 * 8), 256, 0, stream>>>(images, imgbf);
    premask_kernel<<<NBLK_ * NC_, 128, 0, stream>>>(mask, pmaskb, maskflag);
    csr_build_kernel<<<1, 512, 0, stream>>>(idx0, csr_off);
    csr_fill<<<BN_, 64, 0, stream>>>(idx0, csr_off, csr_perm);
    concat_kernel<<<(B_ * NE_ * D_) / 256, 256, 0, stream>>>(nodes, edges, ne);

    for (int l = 0; l < L_; ++l) {
        const unsigned short* wTl = wT + (size_t)l * LAYER_W;
        const float* bqkv_l = bqkv + (size_t)l * 3 * D_;

        // ---- cross attention ----
        ln_kernel<<<B_ * NE_, 256, 0, stream>>>(ne, lnbuf, ln1_g + l * D_, ln1_b + l * D_);
        {   // fused Q-proj + KV-proj in one dispatch
            GArgs gq { lnbuf, wTl + OFF_Q, bqkv_l, nullptr, qb, 256, 256, 256, 1, 4 };
            GArgs gkv{ imgbf, wTl + OFF_K, bqkv_l + D_, nullptr, kvb, 256, 512, 256, 1, 8 };
            int nb0 = (B_ * NE_ / 64) * 4;          // 288
            int nb1 = (B_ * HW_ / 64) * 8;          // 1568
            mgemm2_kernel<<<nb0 + nb1, 256, 0, stream>>>(gq, gkv, nb0);
        }
        attn_kernel<<<NBLK_, 128, 0, stream>>>(qb, kvb, pmaskb, maskflag, ctxb);
        launch_mgemm(stream, 2, 0, ctxb, D_, wTl + OFF_WO, bo + l * D_, nullptr, ne, ls1 + l * D_,
                     ne, D_, B_ * NE_, D_, D_);

        // ---- GAT ----
        ln2enc_kernel<<<B_ * NE_, 256, 0, stream>>>(ne, ln2_g + l * D_, ln2_b + l * D_,
                                                    node_enc, edge_enc, nodes_f, edges_f);
        {   // fused gn12 (nodes) + We (edges) in one dispatch
            GArgs gn { nodes_f, wTl + OFF_WN1, bn1 + l * D_, bn2 + l * D_, gn12, 256, 512, 256, 0, 8 };
            GArgs ge { edges_f, wTl + OFF_WE,  be + l * D_,  nullptr,      hid,  256, 256, 256, 1, 4 };
            int nb0 = (BN_ / 64) * 8;               // 64
            int nb1 = (BE_ / 64) * 4;               // 256
            mgemm2_kernel<<<nb0 + nb1, 256, 0, stream>>>(gn, ge, nb0);
        }
        hidden_kernel<<<BE_, 256, 0, stream>>>(gn12, hid, idx0, attn_p + (size_t)l * H_ * DH_, pres);
        // WEO GEMM with fused vin epilogue
        mgemm_weo_kernel<<<dim3(4, BE_ / 64), 256, 0, stream>>>(
            hid, wTl + OFF_WEO, beo + l * D_, nodes_f, idx1, new_edges, vin);
        launch_mgemm(stream, 0, 0, vin, D_, wTl + OFF_WNO, bno + l * D_, nullptr, nullptr, nullptr,
                     valsb, D_, BE_, D_, D_);
        // fused nodeagg (CSR softmax-aggregate) + gat residual + LN3
        gatagg_ln_kernel<<<B_ * NE_, 256, 0, stream>>>(valsb, pres, csr_off, csr_perm,
                                                       new_edges, ls2 + l * D_,
                                                       ln3_g + l * D_, ln3_b + l * D_, ne, lnbuf);

        // ---- FFN ----
        mgemm128_kernel<1><<<(B_ * NE_ / 128) * (FF_ / 128), 256, 0, stream>>>(
            lnbuf, 256, wTl + OFF_W1, b1 + l * FF_, ffnh, FF_, 256, FF_ / 128);
        launch_mgemm(stream, 2, 0, ffnh, FF_, wTl + OFF_W2, b2 + l * D_, nullptr, ne, ls3 + l * D_,
                     ne, D_, B_ * NE_, D_, FF_);
    }
}

// Round 12
// 588.976 us; speedup vs baseline: 1.0016x; 1.0016x over previous
//
#include <hip/hip_runtime.h>
#include <math.h>

// ---- problem constants ----
static constexpr int B_  = 16;
static constexpr int N_  = 32;
static constexpr int E_  = 256;
static constexpr int D_  = 256;
static constexpr int H_  = 8;
static constexpr int HW_ = 784;
static constexpr int L_  = 4;
static constexpr int DH_ = 32;
static constexpr int FF_ = 1024;
static constexpr int BN_ = 512;
static constexpr int BE_ = 4096;
static constexpr int NE_ = 288;   // N+E
static constexpr int NC_ = 13;    // key chunks of 64 (784 -> 13)
static constexpr int NBLK_ = B_ * H_ * 9;   // 1152 attention blocks
static constexpr size_t KVSZ_ = (size_t)B_ * HW_ * 512;   // per-layer K|V buffer (bf16 elems)
#define SCALE_ 0.17677669529663687f

// per-layer transposed-weight block (bf16 elems)
static constexpr size_t LAYER_W = 1114112;  // 9*65536 + 2*262144
static constexpr size_t OFF_Q   = 0;
static constexpr size_t OFF_WO  = 196608;
static constexpr size_t OFF_WN1 = 262144;   // WN1 then WN2 contiguous -> fused N=512 GEMM
static constexpr size_t OFF_WE  = 393216;
static constexpr size_t OFF_WEO = 458752;
static constexpr size_t OFF_WNO = 524288;
static constexpr size_t OFF_W1  = 589824;
static constexpr size_t OFF_W2  = 851968;

typedef __attribute__((ext_vector_type(8))) short bf16x8;
typedef __attribute__((ext_vector_type(4))) float f32x4;

typedef __attribute__((address_space(1))) const unsigned int gas_uint;
typedef __attribute__((address_space(3))) unsigned int las_uint;

__device__ __forceinline__ void gload16(const unsigned short* g, unsigned short* lds) {
    __builtin_amdgcn_global_load_lds((gas_uint*)g, (las_uint*)lds, 16, 0, 0);
}

__device__ __forceinline__ float gelu_f(float x) {
    return 0.5f * x * (1.0f + erff(x * 0.7071067811865476f));
}

__device__ __forceinline__ unsigned short f2bf(float x) {
    unsigned u = __float_as_uint(x);
    u += 0x7FFFu + ((u >> 16) & 1u);   // RNE
    return (unsigned short)(u >> 16);
}
__device__ __forceinline__ unsigned pack2bf(float a, float b) {
    return (unsigned)f2bf(a) | ((unsigned)f2bf(b) << 16);
}
__device__ __forceinline__ float bf2f(unsigned short u) {
    return __uint_as_float(((unsigned)u) << 16);
}

// ---------------- elementwise / LN kernels ----------------

__global__ void concat_kernel(const float* __restrict__ nodes, const float* __restrict__ edges,
                              float* __restrict__ ne) {
    int tid = blockIdx.x * 256 + threadIdx.x;   // B*NE*D
    int d = tid & 255;
    int row = tid >> 8;
    int b = row / NE_, pos = row % NE_;
    float v = (pos < N_) ? nodes[(size_t)(b * N_ + pos) * D_ + d]
                         : edges[(size_t)(b * E_ + (pos - N_)) * D_ + d];
    ne[tid] = v;
}

// images f32 -> bf16 (once per call)
__global__ void imgcast_kernel(const float* __restrict__ img, unsigned short* __restrict__ out) {
    int tid = blockIdx.x * 256 + threadIdx.x;   // (B*HW*D)/8 threads
    const float* p = img + (size_t)tid * 8;
    float4 a = *(const float4*)(p);
    float4 b = *(const float4*)(p + 4);
    uint4 o = make_uint4(pack2bf(a.x, a.y), pack2bf(a.z, a.w),
                         pack2bf(b.x, b.y), pack2bf(b.z, b.w));
    *(uint4*)&out[(size_t)tid * 8] = o;
}

// ---- zero init for mask flag ----
__global__ void zeroinit_kernel(int* maskflag) {
    if (threadIdx.x == 0 && blockIdx.x == 0) *maskflag = 0;
}

// ---- mask zero check: OR-reduce all bits; sets flag if any nonzero ----
__global__ __launch_bounds__(256) void maskchk_kernel(const float* __restrict__ mask,
                                                      int* __restrict__ flag) {
    const size_t total = (size_t)B_ * H_ * NE_ * HW_ / 4;   // uint4 count
    const uint4* m = (const uint4*)mask;
    unsigned acc = 0;
    for (size_t i = (size_t)blockIdx.x * 256 + threadIdx.x; i < total; i += (size_t)gridDim.x * 256) {
        uint4 v = m[i];
        acc |= v.x | v.y | v.z | v.w;
    }
    unsigned long long bal = __ballot(acc != 0);
    if (bal != 0 && (threadIdx.x & 63) == (__ffsll((long long)bal) - 1))
        atomicOr(flag, 1);
}

// ---- mask preprocessing: f32 [B,H,NE,HW] -> bf16 fragment layout ----
__global__ __launch_bounds__(128) void premask_kernel(const float* __restrict__ mask,
                                                      unsigned short* __restrict__ pmask,
                                                      const int* __restrict__ flag) {
    if (*flag == 0) return;
    const int bid = blockIdx.x;          // bq*NC_ + c
    const int c = bid % NC_;
    const int bq = bid / NC_;
    const int h = bq & 7;
    const int qt = (bq >> 3) % 9;
    const int b = (bq >> 3) / 9;
    const int q0 = qt * 32, c0 = c * 64;
    __shared__ float ts[32][68];
    const int t = threadIdx.x;
    const int row = t >> 2, cg = (t & 3) * 16;
    const float* mrow = mask + ((size_t)(b * H_ + h) * NE_ + q0 + row) * (size_t)HW_;
    #pragma unroll
    for (int i = 0; i < 4; ++i) {
        int col = c0 + cg + i * 4;
        float4 m4;
        if (col + 4 <= HW_) {
            m4 = *(const float4*)(mrow + col);
        } else {
            m4.x = (col + 0 < HW_) ? mrow[col + 0] : -1e30f;
            m4.y = (col + 1 < HW_) ? mrow[col + 1] : -1e30f;
            m4.z = (col + 2 < HW_) ? mrow[col + 2] : -1e30f;
            m4.w = (col + 3 < HW_) ? mrow[col + 3] : -1e30f;
        }
        *(float4*)&ts[row][cg + i * 4] = m4;
    }
    __syncthreads();
    const int w = t >> 6, lg = (t & 63) >> 4, lr = t & 15;
    const int r0 = w * 16 + lg * 4;
    unsigned u[8];
    #pragma unroll
    for (int rg = 0; rg < 4; ++rg) {
        u[rg * 2 + 0] = pack2bf(ts[r0 + rg][0 * 16 + lr], ts[r0 + rg][1 * 16 + lr]);
        u[rg * 2 + 1] = pack2bf(ts[r0 + rg][2 * 16 + lr], ts[r0 + rg][3 * 16 + lr]);
    }
    uint4* dst = (uint4*)(pmask + (size_t)bid * 2048 + t * 16);
    dst[0] = make_uint4(u[0], u[1], u[2], u[3]);
    dst[1] = make_uint4(u[4], u[5], u[6], u[7]);
}

// LN core given the row value already in-register
__device__ __forceinline__ float ln_from_val(float v, int d,
                                             const float* __restrict__ g, const float* __restrict__ bta,
                                             float* sh1, float* sh2) {
    float s = v, s2 = v * v;
    #pragma unroll
    for (int o = 32; o >= 1; o >>= 1) { s += __shfl_down(s, o); s2 += __shfl_down(s2, o); }
    int lane = d & 63, w = d >> 6;
    if (lane == 0) { sh1[w] = s; sh2[w] = s2; }
    __syncthreads();
    if (d == 0) {
        float a = sh1[0] + sh1[1] + sh1[2] + sh1[3];
        float c = sh2[0] + sh2[1] + sh2[2] + sh2[3];
        sh1[0] = a; sh2[0] = c;
    }
    __syncthreads();
    float mean = sh1[0] * (1.0f / D_);
    float var  = sh2[0] * (1.0f / D_) - mean * mean;
    float rstd = rsqrtf(var + 1e-5f);
    return (v - mean) * rstd * g[d] + bta[d];
}

// LN -> bf16 out
__global__ __launch_bounds__(256) void ln_kernel(const float* __restrict__ x,
                                                 unsigned short* __restrict__ y,
                                                 const float* __restrict__ g,
                                                 const float* __restrict__ bta) {
    __shared__ float sh1[4], sh2[4];
    const int row = blockIdx.x, d = threadIdx.x;
    float v = x[(size_t)row * D_ + d];
    y[(size_t)row * D_ + d] = f2bf(ln_from_val(v, d, g, bta, sh1, sh2));
}

// LN2 fused with +enc and node/edge split, bf16 out
__global__ __launch_bounds__(256) void ln2enc_kernel(const float* __restrict__ x,
                                                     const float* __restrict__ g,
                                                     const float* __restrict__ bta,
                                                     const float* __restrict__ node_enc,
                                                     const float* __restrict__ edge_enc,
                                                     unsigned short* __restrict__ nodes_f,
                                                     unsigned short* __restrict__ edges_f) {
    __shared__ float sh1[4], sh2[4];
    const int row = blockIdx.x, d = threadIdx.x;
    float v = x[(size_t)row * D_ + d];
    float val = ln_from_val(v, d, g, bta, sh1, sh2);
    int b = row / NE_, pos = row % NE_;
    if (pos < N_) {
        int rn = b * N_ + pos;
        nodes_f[(size_t)rn * D_ + d] = f2bf(val + node_enc[(size_t)rn * D_ + d]);
    } else {
        int re = b * E_ + (pos - N_);
        edges_f[(size_t)re * D_ + d] = f2bf(val + edge_enc[(size_t)re * D_ + d]);
    }
}

// fused: node-rows aggregate CSR softmax inline; edge-rows read new_edges;
// then ne += ls2*gat and lnbuf = LN3(ne), bf16
__global__ __launch_bounds__(256) void gatagg_ln_kernel(
    const float* __restrict__ vals, const float* __restrict__ pres,
    const int* __restrict__ csr_off, const int* __restrict__ csr_perm,
    const float* __restrict__ new_edges, const float* __restrict__ ls2l,
    const float* __restrict__ g, const float* __restrict__ bta,
    float* __restrict__ ne, unsigned short* __restrict__ lnb) {
    __shared__ float sh1[4], sh2[4];
    __shared__ float sms[8], sden[8];
    const int row = blockIdx.x, d = threadIdx.x;
    int b = row / NE_, pos = row % NE_;
    float gv;
    if (pos < N_) {            // block-uniform branch
        int n = b * N_ + pos;
        int s = csr_off[n], e2 = csr_off[n + 1];
        if (d < 8) {
            float mx = -INFINITY;
            for (int i = s; i < e2; ++i) mx = fmaxf(mx, pres[csr_perm[i] * H_ + d]);
            float sum = 0.f;
            for (int i = s; i < e2; ++i) sum += __expf(pres[csr_perm[i] * H_ + d] - mx);
            sms[d] = mx; sden[d] = sum;
        }
        __syncthreads();
        int h = d >> 5;
        float ms = sms[h];
        float rd = 1.0f / sden[h];
        float acc = 0.f;
        for (int i = s; i < e2; ++i) {
            int e = csr_perm[i];
            acc += vals[(size_t)e * D_ + d] * (__expf(pres[e * H_ + h] - ms) * rd);
        }
        gv = acc;
    } else {
        gv = new_edges[(size_t)(b * E_ + (pos - N_)) * D_ + d];
    }
    float v = ne[(size_t)row * D_ + d] + ls2l[d] * gv;
    ne[(size_t)row * D_ + d] = v;
    lnb[(size_t)row * D_ + d] = f2bf(ln_from_val(v, d, g, bta, sh1, sh2));
}

// ---------------- weight transpose+cast: W[K,N] f32 -> Wt[N,K] bf16 ----------------
// K/V weight tiles go to kvwT [L*512][256] (contiguous across layers for batched KV GEMM)
__global__ __launch_bounds__(256) void wtrans_kernel(
    const float* __restrict__ Wqkv, const float* __restrict__ Wo,
    const float* __restrict__ Wn1,  const float* __restrict__ Wn2,
    const float* __restrict__ We,   const float* __restrict__ Weo,
    const float* __restrict__ Wno,  const float* __restrict__ W1,
    const float* __restrict__ W2,   unsigned short* __restrict__ wT,
    unsigned short* __restrict__ kvwT)
{
    const int bid = blockIdx.x;
    const int l = bid / 1088;
    int tl = bid % 1088;
    const float* src; int ld, K, Nn; unsigned short* dst;
    if (tl < 576) {
        int mid = tl >> 6; tl &= 63;
        K = 256; Nn = 256;
        if (mid == 0) {
            src = Wqkv + (size_t)l * 256 * 768; ld = 768;
            dst = wT + (size_t)l * LAYER_W + OFF_Q;
        } else if (mid < 3) {
            src = Wqkv + (size_t)l * 256 * 768 + mid * 256; ld = 768;
            dst = kvwT + ((size_t)l * 512 + (size_t)(mid - 1) * 256) * 256;
        } else {
            const float* bases[6] = {Wo, Wn1, Wn2, We, Weo, Wno};
            src = bases[mid - 3] + (size_t)l * 65536; ld = 256;
            dst = wT + (size_t)l * LAYER_W + OFF_WO + (size_t)(mid - 3) * 65536;
        }
    } else if (tl < 832) {
        tl -= 576; K = 256; Nn = 1024;
        src = W1 + (size_t)l * 262144; ld = 1024;
        dst = wT + (size_t)l * LAYER_W + OFF_W1;
    } else {
        tl -= 832; K = 1024; Nn = 256;
        src = W2 + (size_t)l * 262144; ld = 256;
        dst = wT + (size_t)l * LAYER_W + OFF_W2;
    }
    const int ntn = Nn >> 5;
    const int k0 = (tl / ntn) << 5, n0 = (tl % ntn) << 5;
    __shared__ float ts[32][33];
    const int t = threadIdx.x;
    const int kl = t >> 5, nl = t & 31;
    #pragma unroll
    for (int rr = 0; rr < 4; ++rr)
        ts[kl + rr * 8][nl] = src[(size_t)(k0 + kl + rr * 8) * ld + n0 + nl];
    __syncthreads();
    const int onl = t >> 3, okl = (t & 7) << 2;
    ushort4 o;
    o.x = f2bf(ts[okl + 0][onl]); o.y = f2bf(ts[okl + 1][onl]);
    o.z = f2bf(ts[okl + 2][onl]); o.w = f2bf(ts[okl + 3][onl]);
    *(ushort4*)&dst[(size_t)(n0 + onl) * K + k0 + okl] = o;
}

// ---------------- 64-tile MFMA GEMM ----------------
// Linear LDS [64][64] with XOR swizzle: swizzled col (halves) = col ^ ((row&7)<<3).

struct GArgs {
    const unsigned short* A;
    const unsigned short* Bt;
    const float* bias;
    const float* bias2;
    void* C;
    int lda, ldc, K, outbf, nbx;
};

template<int MODE, int OUTBF>
__global__ __launch_bounds__(256) void mgemm_kernel(
    const unsigned short* __restrict__ A, int lda,
    const unsigned short* __restrict__ Bt,
    const float* __restrict__ bias,
    const float* __restrict__ bias2,
    const float* __restrict__ res,
    const float* __restrict__ ls,
    void* __restrict__ Cv, int ldc, int K)
{
    __shared__ __align__(16) unsigned short As[64 * 64];
    __shared__ __align__(16) unsigned short Bs[64 * 64];
    const int m0 = blockIdx.y * 64, n0 = blockIdx.x * 64;
    const int t = threadIdx.x;
    const int l = t & 63, w = t >> 6;
    const int wr = (w >> 1) * 32, wc = (w & 1) * 32;
    const int frow = l & 15, kg = l >> 4;
    const int srow = w * 8 + (l >> 3);
    const int scolh = 8 * ((l & 7) ^ (l >> 3));
    const int ldsoff = w * 512;
    const int sw = (frow & 7) << 3;
    f32x4 acc[2][2];
    acc[0][0] = (f32x4){0.f,0.f,0.f,0.f}; acc[0][1] = acc[0][0];
    acc[1][0] = acc[0][0];                acc[1][1] = acc[0][0];
    for (int k0 = 0; k0 < K; k0 += 64) {
        const unsigned short* ga = A  + (size_t)(m0 + srow) * lda + k0 + scolh;
        const unsigned short* gb = Bt + (size_t)(n0 + srow) * K   + k0 + scolh;
        gload16(ga,                As + ldsoff);
        gload16(ga + 32 * lda,     As + ldsoff + 2048);
        gload16(gb,                Bs + ldsoff);
        gload16(gb + (size_t)32 * K, Bs + ldsoff + 2048);
        __syncthreads();
        #pragma unroll
        for (int kk = 0; kk < 2; ++kk) {
            const int off = (kk * 32 + kg * 8) ^ sw;
            bf16x8 af0 = *(const bf16x8*)&As[(wr + frow) * 64 + off];
            bf16x8 af1 = *(const bf16x8*)&As[(wr + 16 + frow) * 64 + off];
            bf16x8 bf0 = *(const bf16x8*)&Bs[(wc + frow) * 64 + off];
            bf16x8 bf1 = *(const bf16x8*)&Bs[(wc + 16 + frow) * 64 + off];
            acc[0][0] = __builtin_amdgcn_mfma_f32_16x16x32_bf16(af0, bf0, acc[0][0], 0, 0, 0);
            acc[0][1] = __builtin_amdgcn_mfma_f32_16x16x32_bf16(af0, bf1, acc[0][1], 0, 0, 0);
            acc[1][0] = __builtin_amdgcn_mfma_f32_16x16x32_bf16(af1, bf0, acc[1][0], 0, 0, 0);
            acc[1][1] = __builtin_amdgcn_mfma_f32_16x16x32_bf16(af1, bf1, acc[1][1], 0, 0, 0);
        }
        __syncthreads();
    }
    #pragma unroll
    for (int fr = 0; fr < 2; ++fr) {
        #pragma unroll
        for (int fc = 0; fc < 2; ++fc) {
            int n = n0 + wc + fc * 16 + frow;
            float bv = (bias2 != nullptr && n >= 256) ? bias2[n - 256] : bias[n];
            float lv = (MODE == 2) ? ls[n] : 0.f;
            #pragma unroll
            for (int rg = 0; rg < 4; ++rg) {
                int m = m0 + wr + fr * 16 + kg * 4 + rg;
                float vv = acc[fr][fc][rg] + bv;
                if (MODE == 1) vv = gelu_f(vv);
                if (MODE == 2) vv = res[(size_t)m * ldc + n] + lv * vv;
                if (OUTBF) ((unsigned short*)Cv)[(size_t)m * ldc + n] = f2bf(vv);
                else       ((float*)Cv)[(size_t)m * ldc + n] = vv;
            }
        }
    }
}

// WEO GEMM with fused vin epilogue
__global__ __launch_bounds__(256) void mgemm_weo_kernel(
    const unsigned short* __restrict__ A,
    const unsigned short* __restrict__ Bt,
    const float* __restrict__ bias,
    const unsigned short* __restrict__ nodes_f,
    const int* __restrict__ idx1,
    float* __restrict__ new_edges,
    unsigned short* __restrict__ vin)
{
    __shared__ __align__(16) unsigned short As[64 * 64];
    __shared__ __align__(16) unsigned short Bs[64 * 64];
    const int m0 = blockIdx.y * 64, n0 = blockIdx.x * 64;
    const int t = threadIdx.x;
    const int l = t & 63, w = t >> 6;
    const int wr = (w >> 1) * 32, wc = (w & 1) * 32;
    const int frow = l & 15, kg = l >> 4;
    const int srow = w * 8 + (l >> 3);
    const int scolh = 8 * ((l & 7) ^ (l >> 3));
    const int ldsoff = w * 512;
    const int sw = (frow & 7) << 3;
    f32x4 acc[2][2];
    acc[0][0] = (f32x4){0.f,0.f,0.f,0.f}; acc[0][1] = acc[0][0];
    acc[1][0] = acc[0][0];                acc[1][1] = acc[0][0];
    for (int k0 = 0; k0 < 256; k0 += 64) {
        const unsigned short* ga = A  + (size_t)(m0 + srow) * 256 + k0 + scolh;
        const unsigned short* gb = Bt + (size_t)(n0 + srow) * 256 + k0 + scolh;
        gload16(ga,                 As + ldsoff);
        gload16(ga + 32 * 256,      As + ldsoff + 2048);
        gload16(gb,                 Bs + ldsoff);
        gload16(gb + 32 * 256,      Bs + ldsoff + 2048);
        __syncthreads();
        #pragma unroll
        for (int kk = 0; kk < 2; ++kk) {
            const int off = (kk * 32 + kg * 8) ^ sw;
            bf16x8 af0 = *(const bf16x8*)&As[(wr + frow) * 64 + off];
            bf16x8 af1 = *(const bf16x8*)&As[(wr + 16 + frow) * 64 + off];
            bf16x8 bf0 = *(const bf16x8*)&Bs[(wc + frow) * 64 + off];
            bf16x8 bf1 = *(const bf16x8*)&Bs[(wc + 16 + frow) * 64 + off];
            acc[0][0] = __builtin_amdgcn_mfma_f32_16x16x32_bf16(af0, bf0, acc[0][0], 0, 0, 0);
            acc[0][1] = __builtin_amdgcn_mfma_f32_16x16x32_bf16(af0, bf1, acc[0][1], 0, 0, 0);
            acc[1][0] = __builtin_amdgcn_mfma_f32_16x16x32_bf16(af1, bf0, acc[1][0], 0, 0, 0);
            acc[1][1] = __builtin_amdgcn_mfma_f32_16x16x32_bf16(af1, bf1, acc[1][1], 0, 0, 0);
        }
        __syncthreads();
    }
    #pragma unroll
    for (int fr = 0; fr < 2; ++fr) {
        #pragma unroll
        for (int rg = 0; rg < 4; ++rg) {
            int m = m0 + wr + fr * 16 + kg * 4 + rg;
            int src = idx1[m];
            #pragma unroll
            for (int fc = 0; fc < 2; ++fc) {
                int n = n0 + wc + fc * 16 + frow;
                float vv = acc[fr][fc][rg] + bias[n];
                new_edges[(size_t)m * 256 + n] = vv;
                vin[(size_t)m * 256 + n] = f2bf(bf2f(nodes_f[(size_t)src * 256 + n]) + vv);
            }
        }
    }
}

// dual-descriptor GEMM: two independent MODE-0 GEMMs in one dispatch
__global__ __launch_bounds__(256) void mgemm2_kernel(GArgs g0, GArgs g1, int nblk0) {
    const bool first = (int)blockIdx.x < nblk0;
    GArgs g = first ? g0 : g1;
    const int bid = first ? blockIdx.x : blockIdx.x - nblk0;
    __shared__ __align__(16) unsigned short As[64 * 64];
    __shared__ __align__(16) unsigned short Bs[64 * 64];
    const int m0 = (bid / g.nbx) * 64, n0 = (bid % g.nbx) * 64;
    const int t = threadIdx.x;
    const int l = t & 63, w = t >> 6;
    const int wr = (w >> 1) * 32, wc = (w & 1) * 32;
    const int frow = l & 15, kg = l >> 4;
    const int srow = w * 8 + (l >> 3);
    const int scolh = 8 * ((l & 7) ^ (l >> 3));
    const int ldsoff = w * 512;
    const int sw = (frow & 7) << 3;
    f32x4 acc[2][2];
    acc[0][0] = (f32x4){0.f,0.f,0.f,0.f}; acc[0][1] = acc[0][0];
    acc[1][0] = acc[0][0];                acc[1][1] = acc[0][0];
    for (int k0 = 0; k0 < g.K; k0 += 64) {
        const unsigned short* ga = g.A  + (size_t)(m0 + srow) * g.lda + k0 + scolh;
        const unsigned short* gb = g.Bt + (size_t)(n0 + srow) * g.K   + k0 + scolh;
        gload16(ga,                  As + ldsoff);
        gload16(ga + 32 * g.lda,     As + ldsoff + 2048);
        gload16(gb,                  Bs + ldsoff);
        gload16(gb + (size_t)32 * g.K, Bs + ldsoff + 2048);
        __syncthreads();
        #pragma unroll
        for (int kk = 0; kk < 2; ++kk) {
            const int off = (kk * 32 + kg * 8) ^ sw;
            bf16x8 af0 = *(const bf16x8*)&As[(wr + frow) * 64 + off];
            bf16x8 af1 = *(const bf16x8*)&As[(wr + 16 + frow) * 64 + off];
            bf16x8 bf0 = *(const bf16x8*)&Bs[(wc + frow) * 64 + off];
            bf16x8 bf1 = *(const bf16x8*)&Bs[(wc + 16 + frow) * 64 + off];
            acc[0][0] = __builtin_amdgcn_mfma_f32_16x16x32_bf16(af0, bf0, acc[0][0], 0, 0, 0);
            acc[0][1] = __builtin_amdgcn_mfma_f32_16x16x32_bf16(af0, bf1, acc[0][1], 0, 0, 0);
            acc[1][0] = __builtin_amdgcn_mfma_f32_16x16x32_bf16(af1, bf0, acc[1][0], 0, 0, 0);
            acc[1][1] = __builtin_amdgcn_mfma_f32_16x16x32_bf16(af1, bf1, acc[1][1], 0, 0, 0);
        }
        __syncthreads();
    }
    #pragma unroll
    for (int fr = 0; fr < 2; ++fr) {
        #pragma unroll
        for (int fc = 0; fc < 2; ++fc) {
            int n = n0 + wc + fc * 16 + frow;
            float bv = (g.bias2 != nullptr && n >= 256) ? g.bias2[n - 256] : g.bias[n];
            #pragma unroll
            for (int rg = 0; rg < 4; ++rg) {
                int m = m0 + wr + fr * 16 + kg * 4 + rg;
                float vv = acc[fr][fc][rg] + bv;
                if (g.outbf) ((unsigned short*)g.C)[(size_t)m * g.ldc + n] = f2bf(vv);
                else         ((float*)g.C)[(size_t)m * g.ldc + n] = vv;
            }
        }
    }
}

// ---------------- 128-tile MFMA GEMM: generic (MODE 0/1) ----------------
template<int MODE>
__global__ __launch_bounds__(256) void mgemm128_kernel(
    const unsigned short* __restrict__ A, int lda,
    const unsigned short* __restrict__ Bt,
    const float* __restrict__ bias,
    unsigned short* __restrict__ C, int ldc, int K, int nbx)
{
    __shared__ __align__(16) unsigned short As[128 * 64];
    __shared__ __align__(16) unsigned short Bs[128 * 64];
    const int bid = blockIdx.x;
    const int m0 = (bid / nbx) * 128, n0 = (bid % nbx) * 128;
    const int t = threadIdx.x;
    const int l = t & 63, w = t >> 6;
    const int wr = (w >> 1) * 64, wc = (w & 1) * 64;
    const int frow = l & 15, kg = l >> 4;
    const int srow = w * 8 + (l >> 3);
    const int scolh = 8 * ((l & 7) ^ (l >> 3));
    const int ldsoff = w * 512;
    const int sw = (frow & 7) << 3;
    f32x4 acc[4][4];
    #pragma unroll
    for (int i = 0; i < 4; ++i)
        #pragma unroll
        for (int j = 0; j < 4; ++j) acc[i][j] = (f32x4){0.f, 0.f, 0.f, 0.f};
    for (int k0 = 0; k0 < K; k0 += 64) {
        #pragma unroll
        for (int j = 0; j < 4; ++j) {
            gload16(A  + (size_t)(m0 + j * 32 + srow) * lda + k0 + scolh, As + j * 2048 + ldsoff);
            gload16(Bt + (size_t)(n0 + j * 32 + srow) * K   + k0 + scolh, Bs + j * 2048 + ldsoff);
        }
        __syncthreads();
        #pragma unroll
        for (int kk = 0; kk < 2; ++kk) {
            const int off = (kk * 32 + kg * 8) ^ sw;
            bf16x8 af[4], bf[4];
            #pragma unroll
            for (int i = 0; i < 4; ++i) {
                af[i] = *(const bf16x8*)&As[(wr + i * 16 + frow) * 64 + off];
                bf[i] = *(const bf16x8*)&Bs[(wc + i * 16 + frow) * 64 + off];
            }
            #pragma unroll
            for (int i = 0; i < 4; ++i)
                #pragma unroll
                for (int j = 0; j < 4; ++j)
                    acc[i][j] = __builtin_amdgcn_mfma_f32_16x16x32_bf16(af[i], bf[j], acc[i][j], 0, 0, 0);
        }
        __syncthreads();
    }
    #pragma unroll
    for (int fr = 0; fr < 4; ++fr) {
        #pragma unroll
        for (int fc = 0; fc < 4; ++fc) {
            int n = n0 + wc + fc * 16 + frow;
            float bv = bias[n];
            #pragma unroll
            for (int rg = 0; rg < 4; ++rg) {
                int m = m0 + wr + fr * 16 + kg * 4 + rg;
                float vv = acc[fr][fc][rg] + bv;
                if (MODE == 1) vv = gelu_f(vv);
                C[(size_t)m * ldc + n] = f2bf(vv);
            }
        }
    }
}

// ---------------- batched all-layer K/V projection (128-tile) ----------------
// M=B*HW, N=2048 (4 layers x 512), K=256. Output remapped to per-layer
// contiguous [B*HW][512] buffers (layer = n>>9) -- preserves attn L2 locality.
__global__ __launch_bounds__(256) void mgemmkv_kernel(
    const unsigned short* __restrict__ A,
    const unsigned short* __restrict__ kvwT,
    const float* __restrict__ bqkv,
    unsigned short* __restrict__ kvall)
{
    __shared__ __align__(16) unsigned short As[128 * 64];
    __shared__ __align__(16) unsigned short Bs[128 * 64];
    const int bid = blockIdx.x;
    const int m0 = (bid / 16) * 128, n0 = (bid % 16) * 128;
    const int t = threadIdx.x;
    const int l = t & 63, w = t >> 6;
    const int wr = (w >> 1) * 64, wc = (w & 1) * 64;
    const int frow = l & 15, kg = l >> 4;
    const int srow = w * 8 + (l >> 3);
    const int scolh = 8 * ((l & 7) ^ (l >> 3));
    const int ldsoff = w * 512;
    const int sw = (frow & 7) << 3;
    f32x4 acc[4][4];
    #pragma unroll
    for (int i = 0; i < 4; ++i)
        #pragma unroll
        for (int j = 0; j < 4; ++j) acc[i][j] = (f32x4){0.f, 0.f, 0.f, 0.f};
    for (int k0 = 0; k0 < 256; k0 += 64) {
        #pragma unroll
        for (int j = 0; j < 4; ++j) {
            gload16(A    + (size_t)(m0 + j * 32 + srow) * 256 + k0 + scolh, As + j * 2048 + ldsoff);
            gload16(kvwT + (size_t)(n0 + j * 32 + srow) * 256 + k0 + scolh, Bs + j * 2048 + ldsoff);
        }
        __syncthreads();
        #pragma unroll
        for (int kk = 0; kk < 2; ++kk) {
            const int off = (kk * 32 + kg * 8) ^ sw;
            bf16x8 af[4], bf[4];
            #pragma unroll
            for (int i = 0; i < 4; ++i) {
                af[i] = *(const bf16x8*)&As[(wr + i * 16 + frow) * 64 + off];
                bf[i] = *(const bf16x8*)&Bs[(wc + i * 16 + frow) * 64 + off];
            }
            #pragma unroll
            for (int i = 0; i < 4; ++i)
                #pragma unroll
                for (int j = 0; j < 4; ++j)
                    acc[i][j] = __builtin_amdgcn_mfma_f32_16x16x32_bf16(af[i], bf[j], acc[i][j], 0, 0, 0);
        }
        __syncthreads();
    }
    #pragma unroll
    for (int fr = 0; fr < 4; ++fr) {
        #pragma unroll
        for (int fc = 0; fc < 4; ++fc) {
            int n = n0 + wc + fc * 16 + frow;
            int layer = n >> 9, nn = n & 511;
            float bv = bqkv[layer * 768 + 256 + nn];
            unsigned short* dst = kvall + (size_t)layer * KVSZ_ + nn;
            #pragma unroll
            for (int rg = 0; rg < 4; ++rg) {
                int m = m0 + wr + fr * 16 + kg * 4 + rg;
                dst[(size_t)m * 512] = f2bf(acc[fr][fc][rg] + bv);
            }
        }
    }
}

// ---------------- MFMA flash attention with fused Q-projection ----------------
// 1152 blocks x 128 threads. Block = one (b,h) x 32 q-rows (2 waves x 16 rows).
// Prologue computes Q tile from lnbuf (bf16) x Wq_head via MFMA, staging in the
// (not-yet-used) Ks/Vs LDS region. kv: [B*HW][512] (K cols 0-255, V 256-511).
__global__ __launch_bounds__(128) void attn_kernel(
    const unsigned short* __restrict__ lnb, const unsigned short* __restrict__ wq,
    const float* __restrict__ bqkv_l,
    const unsigned short* __restrict__ kv,
    const unsigned short* __restrict__ pmask, const int* __restrict__ maskflag,
    unsigned short* __restrict__ ctx)
{
    const int bid = blockIdx.x;
    const int h = bid & 7;
    const int qt = (bid >> 3) % 9;
    const int b = (bid >> 3) / 9;
    const int q0 = qt * 32;
    const int t = threadIdx.x;
    const int w = t >> 6, l = t & 63;
    const int lr = l & 15, lg = l >> 4;
    const int hasmask = *maskflag;

    __shared__ unsigned short Ks[2][64][40];
    __shared__ unsigned short Vs[2][32][72];
    __shared__ unsigned short Pl[2][16][72];
    __shared__ unsigned short Qlds[2][16][40];

    // staging assignment (main loop)
    const int kkey = t >> 1, kdh = (t & 1) * 16;          // K: 1 key, 16 dh
    const int vdh = (t & 7) * 4, vk0 = (t >> 3) * 2;      // V: key pairs, 4 dh
    const unsigned short* kbase = kv + ((size_t)b * HW_) * 512 + h * DH_;
    const unsigned short* vbase = kv + ((size_t)b * HW_) * 512 + 256 + h * DH_;
    const uint4* mbase = (const uint4*)(pmask + (size_t)bid * NC_ * 2048 + t * 16);

    uint4 kq0, kq1;
    ushort4 va[2], vb4[2];
    uint4 mc0 = make_uint4(0,0,0,0), mc1 = mc0, mn0 = mc0, mn1 = mc0;

    auto issue_kv = [&](int c0) {
        {
            int key = c0 + kkey;
            bool ok = key < HW_;
            const unsigned short* kp = kbase + (size_t)(ok ? key : 0) * 512 + kdh;
            kq0 = *(const uint4*)(kp);
            kq1 = *(const uint4*)(kp + 8);
            if (!ok) { kq0 = make_uint4(0,0,0,0); kq1 = kq0; }
        }
        #pragma unroll
        for (int r = 0; r < 2; ++r) {
            int key = c0 + vk0 + 32 * r;
            bool ok0 = key < HW_, ok1 = (key + 1) < HW_;
            const unsigned short* vp = vbase + (size_t)(ok0 ? key : 0) * 512 + vdh;
            va[r]  = *(const ushort4*)(vp);
            vb4[r] = *(const ushort4*)(vp + (ok1 ? 512 : 0));
            if (!ok0) va[r]  = make_ushort4(0,0,0,0);
            if (!ok1) vb4[r] = make_ushort4(0,0,0,0);
        }
    };
    auto write_kv = [&](int bufi) {
        *(uint4*)&Ks[bufi][kkey][kdh]     = kq0;
        *(uint4*)&Ks[bufi][kkey][kdh + 8] = kq1;
        #pragma unroll
        for (int r = 0; r < 2; ++r) {
            const unsigned short* a = (const unsigned short*)&va[r];
            const unsigned short* c = (const unsigned short*)&vb4[r];
            #pragma unroll
            for (int i = 0; i < 4; ++i)
                *(unsigned*)&Vs[bufi][vdh + i][vk0 + 32 * r] = (unsigned)a[i] | ((unsigned)c[i] << 16);
        }
    };

    // issue chunk-0 K/V global loads early (registers only; hides latency under prologue)
    issue_kv(0);
    if (hasmask) { mc0 = mbase[0]; mc1 = mbase[1]; }

    // ---- Q-projection prologue: Q[32 rows][32 dh] = lnbuf tile x Wq_head^T ----
    bf16x8 qfrag;
    {
        unsigned short* Aln = &Ks[0][0][0];            // [32][264] (reuses Ks/Vs/Pl bytes)
        unsigned short* Wqs = Aln + 32 * 264;          // [32][264]
        const unsigned short* asrc = lnb + (size_t)(b * NE_ + q0) * 256;
        const unsigned short* wsrc = wq + (size_t)(h * DH_) * 256;
        #pragma unroll
        for (int i = 0; i < 8; ++i) {
            int u = t + i * 128;                       // 1024 uint4 total per tile
            int row = u >> 5, col = (u & 31) * 8;
            *(uint4*)&Aln[row * 264 + col] = *(const uint4*)&asrc[(size_t)row * 256 + col];
            *(uint4*)&Wqs[row * 264 + col] = *(const uint4*)&wsrc[(size_t)row * 256 + col];
        }
        __syncthreads();
        f32x4 qa[2];
        qa[0] = (f32x4){0.f, 0.f, 0.f, 0.f}; qa[1] = qa[0];
        #pragma unroll
        for (int kk = 0; kk < 8; ++kk) {
            bf16x8 af = *(const bf16x8*)&Aln[(w * 16 + lr) * 264 + kk * 32 + lg * 8];
            #pragma unroll
            for (int fc = 0; fc < 2; ++fc) {
                bf16x8 bf = *(const bf16x8*)&Wqs[(fc * 16 + lr) * 264 + kk * 32 + lg * 8];
                qa[fc] = __builtin_amdgcn_mfma_f32_16x16x32_bf16(af, bf, qa[fc], 0, 0, 0);
            }
        }
        __syncthreads();   // all prologue LDS reads done; Ks region reusable
        #pragma unroll
        for (int fc = 0; fc < 2; ++fc) {
            float bq = bqkv_l[h * DH_ + fc * 16 + lr];
            #pragma unroll
            for (int rg = 0; rg < 4; ++rg)
                Qlds[w][lg * 4 + rg][fc * 16 + lr] = f2bf(qa[fc][rg] + bq);
        }
        __syncthreads();
        qfrag = *(const bf16x8*)&Qlds[w][lr][lg * 8];
    }

    f32x4 oacc[2];
    oacc[0] = (f32x4){0.f, 0.f, 0.f, 0.f}; oacc[1] = oacc[0];
    float m_i[4] = {-INFINITY, -INFINITY, -INFINITY, -INFINITY};
    float l_i[4] = {0.f, 0.f, 0.f, 0.f};

    write_kv(0);
    if (hasmask) { mn0 = mbase[128]; mn1 = mbase[129]; }
    __syncthreads();

    for (int c = 0; c < NC_; ++c) {
        const int c0 = c * 64;
        const int cb = c & 1, nb = cb ^ 1;
        if (c + 1 < NC_) issue_kv(c0 + 64);

        // QK^T: S[16 q, 64 keys]
        f32x4 sacc[4];
        #pragma unroll
        for (int fc = 0; fc < 4; ++fc) {
            sacc[fc] = (f32x4){0.f, 0.f, 0.f, 0.f};
            bf16x8 kf = *(const bf16x8*)&Ks[cb][fc * 16 + lr][lg * 8];
            sacc[fc] = __builtin_amdgcn_mfma_f32_16x16x32_bf16(qfrag, kf, sacc[fc], 0, 0, 0);
        }
        float s[4][4];   // [fc][rg]
        if (hasmask) {
            unsigned uw[8] = {mc0.x, mc0.y, mc0.z, mc0.w, mc1.x, mc1.y, mc1.z, mc1.w};
            #pragma unroll
            for (int rg = 0; rg < 4; ++rg) {
                s[0][rg] = sacc[0][rg] * SCALE_ + bf2f((unsigned short)(uw[rg * 2] & 0xffff));
                s[1][rg] = sacc[1][rg] * SCALE_ + bf2f((unsigned short)(uw[rg * 2] >> 16));
                s[2][rg] = sacc[2][rg] * SCALE_ + bf2f((unsigned short)(uw[rg * 2 + 1] & 0xffff));
                s[3][rg] = sacc[3][rg] * SCALE_ + bf2f((unsigned short)(uw[rg * 2 + 1] >> 16));
            }
            float mloc[4];
            #pragma unroll
            for (int rg = 0; rg < 4; ++rg)
                mloc[rg] = fmaxf(fmaxf(s[0][rg], s[1][rg]), fmaxf(s[2][rg], s[3][rg]));
            #pragma unroll
            for (int off = 1; off < 16; off <<= 1)
                #pragma unroll
                for (int rg = 0; rg < 4; ++rg)
                    mloc[rg] = fmaxf(mloc[rg], __shfl_xor(mloc[rg], off));
            float scl[4], lloc[4];
            #pragma unroll
            for (int rg = 0; rg < 4; ++rg) {
                float mn = fmaxf(m_i[rg], mloc[rg]);
                scl[rg] = __expf(m_i[rg] - mn);
                m_i[rg] = mn;
            }
            #pragma unroll
            for (int rg = 0; rg < 4; ++rg) {
                float acc = 0.f;
                #pragma unroll
                for (int fc = 0; fc < 4; ++fc) {
                    float p = __expf(s[fc][rg] - m_i[rg]);
                    s[fc][rg] = p;
                    acc += p;
                }
                lloc[rg] = acc;
            }
            #pragma unroll
            for (int off = 1; off < 16; off <<= 1)
                #pragma unroll
                for (int rg = 0; rg < 4; ++rg)
                    lloc[rg] += __shfl_xor(lloc[rg], off);
            #pragma unroll
            for (int rg = 0; rg < 4; ++rg) {
                l_i[rg] = l_i[rg] * scl[rg] + lloc[rg];
                oacc[0][rg] *= scl[rg];
                oacc[1][rg] *= scl[rg];
            }
        } else {
            // fixed-max softmax (scores bounded << 88): no max tracking
            const bool tailc = (c == NC_ - 1);
            float lloc[4] = {0.f, 0.f, 0.f, 0.f};
            #pragma unroll
            for (int fc = 0; fc < 4; ++fc) {
                float pad = (tailc && (c0 + fc * 16 + lr) >= HW_) ? -1e30f : 0.f;
                #pragma unroll
                for (int rg = 0; rg < 4; ++rg) {
                    float p = __expf(sacc[fc][rg] * SCALE_ + pad);
                    s[fc][rg] = p;
                    lloc[rg] += p;
                }
            }
            #pragma unroll
            for (int off = 1; off < 16; off <<= 1)
                #pragma unroll
                for (int rg = 0; rg < 4; ++rg)
                    lloc[rg] += __shfl_xor(lloc[rg], off);
            #pragma unroll
            for (int rg = 0; rg < 4; ++rg)
                l_i[rg] += lloc[rg];
        }

        // P -> LDS (wave-private), then PV
        #pragma unroll
        for (int fc = 0; fc < 4; ++fc)
            #pragma unroll
            for (int rg = 0; rg < 4; ++rg)
                Pl[w][lg * 4 + rg][fc * 16 + lr] = f2bf(s[fc][rg]);
        #pragma unroll
        for (int ks2 = 0; ks2 < 2; ++ks2) {
            bf16x8 pf = *(const bf16x8*)&Pl[w][lr][ks2 * 32 + lg * 8];
            #pragma unroll
            for (int d2 = 0; d2 < 2; ++d2) {
                bf16x8 vf = *(const bf16x8*)&Vs[cb][d2 * 16 + lr][ks2 * 32 + lg * 8];
                oacc[d2] = __builtin_amdgcn_mfma_f32_16x16x32_bf16(pf, vf, oacc[d2], 0, 0, 0);
            }
        }

        if (hasmask) {
            mc0 = mn0; mc1 = mn1;
            if (c + 2 < NC_) {
                mn0 = mbase[(c + 2) * 128];
                mn1 = mbase[(c + 2) * 128 + 1];
            }
        }
        if (c + 1 < NC_) {
            write_kv(nb);
            __syncthreads();
        }
    }

    unsigned short* cbase = ctx + ((size_t)(b * NE_ + q0 + w * 16 + lg * 4)) * D_ + h * DH_;
    #pragma unroll
    for (int rg = 0; rg < 4; ++rg) {
        float inv = 1.0f / l_i[rg];
        #pragma unroll
        for (int d2 = 0; d2 < 2; ++d2)
            cbase[(size_t)rg * D_ + d2 * 16 + lr] = f2bf(oacc[d2][rg] * inv);
    }
}

// ---------------- GAT kernels ----------------

__global__ __launch_bounds__(256) void hidden_kernel(
    const float* __restrict__ gn12,
    unsigned short* __restrict__ hid, const int* __restrict__ idx0,
    const float* __restrict__ attn_p_l, float* __restrict__ pres) {
    int e = blockIdx.x;
    int d = threadIdx.x;
    int n = idx0[e];
    float x = bf2f(hid[(size_t)e * D_ + d]) + gn12[(size_t)n * 512 + d] + gn12[(size_t)n * 512 + 256 + d];
    float hv = gelu_f(x);
    hid[(size_t)e * D_ + d] = f2bf(hv);
    float pr = hv * attn_p_l[d];
    #pragma unroll
    for (int o = 1; o < 32; o <<= 1) pr += __shfl_xor(pr, o);
    if ((d & 31) == 0) pres[e * H_ + (d >> 5)] = pr;
}

// ---------------- CSR build (deterministic) ----------------

__global__ __launch_bounds__(512) void csr_build_kernel(const int* __restrict__ idx0,
                                                        int* __restrict__ csr_off) {
    __shared__ int cnt[BN_];
    __shared__ int buf[BN_];
    int t = threadIdx.x;
    cnt[t] = 0;
    __syncthreads();
    #pragma unroll
    for (int i = 0; i < BE_ / 512; ++i)
        atomicAdd(&cnt[idx0[t + i * 512]], 1);
    __syncthreads();
    int c = cnt[t];
    buf[t] = c;
    __syncthreads();
    for (int o = 1; o < BN_; o <<= 1) {
        int add = (t >= o) ? buf[t - o] : 0;
        __syncthreads();
        buf[t] += add;
        __syncthreads();
    }
    csr_off[t] = buf[t] - c;
    if (t == BN_ - 1) csr_off[BN_] = buf[t];
}

__global__ __launch_bounds__(64) void csr_fill(const int* __restrict__ idx0,
                                               const int* __restrict__ csr_off,
                                               int* __restrict__ csr_perm) {
    int n = blockIdx.x;
    int lane = threadIdx.x;
    int w = csr_off[n];
    for (int c0 = 0; c0 < BE_; c0 += 64) {
        int e = c0 + lane;
        bool m = (idx0[e] == n);
        unsigned long long bal = __ballot(m);
        if (m) {
            int pre = __popcll(bal & ((1ull << lane) - 1ull));
            csr_perm[w + pre] = e;
        }
        w += __popcll(bal);
    }
}

// ---------------- host orchestration ----------------

static void launch_mgemm(hipStream_t s, int mode, int outbf,
                         const unsigned short* A, int lda, const unsigned short* Bt,
                         const float* bias, const float* bias2, const float* res, const float* ls,
                         void* C, int ldc, int M, int N, int K) {
    dim3 g(N / 64, M / 64);
    if (mode == 0) {
        if (outbf) mgemm_kernel<0,1><<<g, 256, 0, s>>>(A, lda, Bt, bias, bias2, res, ls, C, ldc, K);
        else       mgemm_kernel<0,0><<<g, 256, 0, s>>>(A, lda, Bt, bias, bias2, res, ls, C, ldc, K);
    } else if (mode == 1) {
        mgemm_kernel<1,1><<<g, 256, 0, s>>>(A, lda, Bt, bias, bias2, res, ls, C, ldc, K);
    } else {
        mgemm_kernel<2,0><<<g, 256, 0, s>>>(A, lda, Bt, bias, bias2, res, ls, C, ldc, K);
    }
}

extern "C" void kernel_launch(void* const* d_in, const int* in_sizes, int n_in,
                              void* d_out, int out_size, void* d_ws, size_t ws_size,
                              hipStream_t stream) {
    const float* nodes    = (const float*)d_in[0];
    const float* edges    = (const float*)d_in[1];
    const float* images   = (const float*)d_in[2];
    const float* mask     = (const float*)d_in[3];
    const float* node_enc = (const float*)d_in[4];
    const float* edge_enc = (const float*)d_in[5];
    const float* ln1_g = (const float*)d_in[6];
    const float* ln1_b = (const float*)d_in[7];
    const float* Wqkv  = (const float*)d_in[8];
    const float* bqkv  = (const float*)d_in[9];
    const float* Wo    = (const float*)d_in[10];
    const float* bo    = (const float*)d_in[11];
    const float* ls1   = (const float*)d_in[12];
    const float* ln2_g = (const float*)d_in[13];
    const float* ln2_b = (const float*)d_in[14];
    const float* Wn1   = (const float*)d_in[15];
    const float* bn1   = (const float*)d_in[16];
    const float* Wn2   = (const float*)d_in[17];
    const float* bn2   = (const float*)d_in[18];
    const float* We    = (const float*)d_in[19];
    const float* be    = (const float*)d_in[20];
    const float* attn_p= (const float*)d_in[21];
    const float* Weo   = (const float*)d_in[22];
    const float* beo   = (const float*)d_in[23];
    const float* Wno   = (const float*)d_in[24];
    const float* bno   = (const float*)d_in[25];
    const float* ls2   = (const float*)d_in[26];
    const float* ln3_g = (const float*)d_in[27];
    const float* ln3_b = (const float*)d_in[28];
    const float* W1    = (const float*)d_in[29];
    const float* b1    = (const float*)d_in[30];
    const float* W2    = (const float*)d_in[31];
    const float* b2    = (const float*)d_in[32];
    const float* ls3   = (const float*)d_in[33];
    const int*   edge_index = (const int*)d_in[34];
    const int* idx0 = edge_index;
    const int* idx1 = edge_index + BE_;

    float* ne = (float*)d_out;   // d_out doubles as the running `ne` buffer

    float* cur = (float*)d_ws;
    auto alloc = [&](size_t nfl) { float* p = cur; cur += nfl; return p; };
    auto allocbf = [&](size_t nbf) { float* p = cur; cur += (nbf + 1) / 2; return (unsigned short*)p; };

    unsigned short* lnbuf   = allocbf((size_t)B_ * NE_ * D_);
    unsigned short* kvall   = allocbf((size_t)L_ * KVSZ_);         // per-layer contiguous K|V
    unsigned short* ffnh    = allocbf((size_t)B_ * NE_ * FF_);
    unsigned short* imgbf   = allocbf((size_t)B_ * HW_ * D_);
    unsigned short* ctxb    = allocbf((size_t)B_ * NE_ * D_);
    unsigned short* nodes_f = allocbf((size_t)BN_ * D_);
    unsigned short* edges_f = allocbf((size_t)BE_ * D_);
    unsigned short* hid     = allocbf((size_t)BE_ * D_);
    unsigned short* vin     = allocbf((size_t)BE_ * D_);
    unsigned short* pmaskb  = allocbf((size_t)NBLK_ * NC_ * 2048); // fragment-layout bf16 mask
    unsigned short* kvwT    = allocbf((size_t)L_ * 512 * 256);     // all-layer K/V weights^T
    float* gn12     = alloc((size_t)BN_ * 512);
    float* pres     = alloc((size_t)BE_ * H_);
    float* new_edges= alloc((size_t)BE_ * D_);
    float* valsb    = alloc((size_t)BE_ * D_);
    int* csr_off  = (int*)cur; cur += BN_ + 4;
    int* csr_perm = (int*)cur; cur += BE_;
    int* maskflag = (int*)cur; cur += 4;
    cur = (float*)(((uintptr_t)cur + 255) & ~(uintptr_t)255);
    unsigned short* wT = (unsigned short*)cur;   // 4 * LAYER_W bf16

    // ---- once-per-call preprocessing ----
    zeroinit_kernel<<<1, 64, 0, stream>>>(maskflag);
    maskchk_kernel<<<2048, 256, 0, stream>>>(mask, maskflag);
    wtrans_kernel<<<4 * 1088, 256, 0, stream>>>(Wqkv, Wo, Wn1, Wn2, We, Weo, Wno, W1, W2, wT, kvwT);
    imgcast_kernel<<<(B_ * HW_ * D_) / (256 * 8), 256, 0, stream>>>(images, imgbf);
    premask_kernel<<<NBLK_ * NC_, 128, 0, stream>>>(mask, pmaskb, maskflag);
    csr_build_kernel<<<1, 512, 0, stream>>>(idx0, csr_off);
    csr_fill<<<BN_, 64, 0, stream>>>(idx0, csr_off, csr_perm);
    concat_kernel<<<(B_ * NE_ * D_) / 256, 256, 0, stream>>>(nodes, edges, ne);
    // batched all-layer K/V projection (per-layer contiguous output)
    mgemmkv_kernel<<<(B_ * HW_ / 128) * 16, 256, 0, stream>>>(imgbf, kvwT, bqkv, kvall);

    for (int l = 0; l < L_; ++l) {
        const unsigned short* wTl = wT + (size_t)l * LAYER_W;
        const float* bqkv_l = bqkv + (size_t)l * 3 * D_;

        // ---- cross attention (Q-projection fused into attn) ----
        ln_kernel<<<B_ * NE_, 256, 0, stream>>>(ne, lnbuf, ln1_g + l * D_, ln1_b + l * D_);
        attn_kernel<<<NBLK_, 128, 0, stream>>>(lnbuf, wTl + OFF_Q, bqkv_l,
                                               kvall + (size_t)l * KVSZ_, pmaskb, maskflag, ctxb);
        launch_mgemm(stream, 2, 0, ctxb, D_, wTl + OFF_WO, bo + l * D_, nullptr, ne, ls1 + l * D_,
                     ne, D_, B_ * NE_, D_, D_);

        // ---- GAT ----
        ln2enc_kernel<<<B_ * NE_, 256, 0, stream>>>(ne, ln2_g + l * D_, ln2_b + l * D_,
                                                    node_enc, edge_enc, nodes_f, edges_f);
        {   // fused gn12 (nodes) + We (edges) in one dispatch
            GArgs gn { nodes_f, wTl + OFF_WN1, bn1 + l * D_, bn2 + l * D_, gn12, 256, 512, 256, 0, 8 };
            GArgs ge { edges_f, wTl + OFF_WE,  be + l * D_,  nullptr,      hid,  256, 256, 256, 1, 4 };
            int nb0 = (BN_ / 64) * 8;               // 64
            int nb1 = (BE_ / 64) * 4;               // 256
            mgemm2_kernel<<<nb0 + nb1, 256, 0, stream>>>(gn, ge, nb0);
        }
        hidden_kernel<<<BE_, 256, 0, stream>>>(gn12, hid, idx0, attn_p + (size_t)l * H_ * DH_, pres);
        mgemm_weo_kernel<<<dim3(4, BE_ / 64), 256, 0, stream>>>(
            hid, wTl + OFF_WEO, beo + l * D_, nodes_f, idx1, new_edges, vin);
        launch_mgemm(stream, 0, 0, vin, D_, wTl + OFF_WNO, bno + l * D_, nullptr, nullptr, nullptr,
                     valsb, D_, BE_, D_, D_);
        gatagg_ln_kernel<<<B_ * NE_, 256, 0, stream>>>(valsb, pres, csr_off, csr_perm,
                                                       new_edges, ls2 + l * D_,
                                                       ln3_g + l * D_, ln3_b + l * D_, ne, lnbuf);

        // ---- FFN ----
        mgemm128_kernel<1><<<(B_ * NE_ / 128) * (FF_ / 128), 256, 0, stream>>>(
            lnbuf, 256, wTl + OFF_W1, b1 + l * FF_, ffnh, FF_, 256, FF_ / 128);
        launch_mgemm(stream, 2, 0, ffnh, FF_, wTl + OFF_W2, b2 + l * D_, nullptr, ne, ls3 + l * D_,
                     ne, D_, B_ * NE_, D_, FF_);
    }
}

// Round 13
// 582.569 us; speedup vs baseline: 1.0126x; 1.0110x over previous
//
#include <hip/hip_runtime.h>
#include <math.h>

// ---- problem constants ----
static constexpr int B_  = 16;
static constexpr int N_  = 32;
static constexpr int E_  = 256;
static constexpr int D_  = 256;
static constexpr int H_  = 8;
static constexpr int HW_ = 784;
static constexpr int L_  = 4;
static constexpr int DH_ = 32;
static constexpr int FF_ = 1024;
static constexpr int BN_ = 512;
static constexpr int BE_ = 4096;
static constexpr int NE_ = 288;   // N+E
static constexpr int NC_ = 13;    // key chunks of 64 (784 -> 13)
static constexpr int NBLK_ = B_ * H_ * 9;   // 1152 attention blocks
static constexpr size_t KVSZ_ = (size_t)B_ * HW_ * 512;   // per-layer K|V buffer (bf16 elems)
#define SCALE_ 0.17677669529663687f

// per-layer transposed-weight block (bf16 elems)
static constexpr size_t LAYER_W = 1114112;  // 9*65536 + 2*262144
static constexpr size_t OFF_Q   = 0;
static constexpr size_t OFF_WO  = 196608;
static constexpr size_t OFF_WN1 = 262144;   // WN1 then WN2 contiguous -> fused N=512 GEMM
static constexpr size_t OFF_WE  = 393216;
static constexpr size_t OFF_WEO = 458752;
static constexpr size_t OFF_WNO = 524288;
static constexpr size_t OFF_W1  = 589824;
static constexpr size_t OFF_W2  = 851968;

typedef __attribute__((ext_vector_type(8))) short bf16x8;
typedef __attribute__((ext_vector_type(4))) float f32x4;

typedef __attribute__((address_space(1))) const unsigned int gas_uint;
typedef __attribute__((address_space(3))) unsigned int las_uint;

__device__ __forceinline__ void gload16(const unsigned short* g, unsigned short* lds) {
    __builtin_amdgcn_global_load_lds((gas_uint*)g, (las_uint*)lds, 16, 0, 0);
}

__device__ __forceinline__ float gelu_f(float x) {
    return 0.5f * x * (1.0f + erff(x * 0.7071067811865476f));
}

__device__ __forceinline__ unsigned short f2bf(float x) {
    unsigned u = __float_as_uint(x);
    u += 0x7FFFu + ((u >> 16) & 1u);   // RNE
    return (unsigned short)(u >> 16);
}
__device__ __forceinline__ unsigned pack2bf(float a, float b) {
    return (unsigned)f2bf(a) | ((unsigned)f2bf(b) << 16);
}
__device__ __forceinline__ float bf2f(unsigned short u) {
    return __uint_as_float(((unsigned)u) << 16);
}

// ---------------- elementwise / LN kernels ----------------

__global__ void concat_kernel(const float* __restrict__ nodes, const float* __restrict__ edges,
                              float* __restrict__ ne) {
    int tid = blockIdx.x * 256 + threadIdx.x;   // B*NE*D
    int d = tid & 255;
    int row = tid >> 8;
    int b = row / NE_, pos = row % NE_;
    float v = (pos < N_) ? nodes[(size_t)(b * N_ + pos) * D_ + d]
                         : edges[(size_t)(b * E_ + (pos - N_)) * D_ + d];
    ne[tid] = v;
}

// ---- zero init for mask flag ----
__global__ void zeroinit_kernel(int* maskflag) {
    if (threadIdx.x == 0 && blockIdx.x == 0) *maskflag = 0;
}

// ---- mask zero check: OR-reduce all bits; sets flag if any nonzero ----
__global__ __launch_bounds__(256) void maskchk_kernel(const float* __restrict__ mask,
                                                      int* __restrict__ flag) {
    const size_t total = (size_t)B_ * H_ * NE_ * HW_ / 4;   // uint4 count
    const uint4* m = (const uint4*)mask;
    unsigned acc = 0;
    for (size_t i = (size_t)blockIdx.x * 256 + threadIdx.x; i < total; i += (size_t)gridDim.x * 256) {
        uint4 v = m[i];
        acc |= v.x | v.y | v.z | v.w;
    }
    unsigned long long bal = __ballot(acc != 0);
    if (bal != 0 && (threadIdx.x & 63) == (__ffsll((long long)bal) - 1))
        atomicOr(flag, 1);
}

// ---- mask preprocessing: f32 [B,H,NE,HW] -> bf16 fragment layout ----
__global__ __launch_bounds__(128) void premask_kernel(const float* __restrict__ mask,
                                                      unsigned short* __restrict__ pmask,
                                                      const int* __restrict__ flag) {
    if (*flag == 0) return;
    const int bid = blockIdx.x;          // bq*NC_ + c
    const int c = bid % NC_;
    const int bq = bid / NC_;
    const int h = bq & 7;
    const int qt = (bq >> 3) % 9;
    const int b = (bq >> 3) / 9;
    const int q0 = qt * 32, c0 = c * 64;
    __shared__ float ts[32][68];
    const int t = threadIdx.x;
    const int row = t >> 2, cg = (t & 3) * 16;
    const float* mrow = mask + ((size_t)(b * H_ + h) * NE_ + q0 + row) * (size_t)HW_;
    #pragma unroll
    for (int i = 0; i < 4; ++i) {
        int col = c0 + cg + i * 4;
        float4 m4;
        if (col + 4 <= HW_) {
            m4 = *(const float4*)(mrow + col);
        } else {
            m4.x = (col + 0 < HW_) ? mrow[col + 0] : -1e30f;
            m4.y = (col + 1 < HW_) ? mrow[col + 1] : -1e30f;
            m4.z = (col + 2 < HW_) ? mrow[col + 2] : -1e30f;
            m4.w = (col + 3 < HW_) ? mrow[col + 3] : -1e30f;
        }
        *(float4*)&ts[row][cg + i * 4] = m4;
    }
    __syncthreads();
    const int w = t >> 6, lg = (t & 63) >> 4, lr = t & 15;
    const int r0 = w * 16 + lg * 4;
    unsigned u[8];
    #pragma unroll
    for (int rg = 0; rg < 4; ++rg) {
        u[rg * 2 + 0] = pack2bf(ts[r0 + rg][0 * 16 + lr], ts[r0 + rg][1 * 16 + lr]);
        u[rg * 2 + 1] = pack2bf(ts[r0 + rg][2 * 16 + lr], ts[r0 + rg][3 * 16 + lr]);
    }
    uint4* dst = (uint4*)(pmask + (size_t)bid * 2048 + t * 16);
    dst[0] = make_uint4(u[0], u[1], u[2], u[3]);
    dst[1] = make_uint4(u[4], u[5], u[6], u[7]);
}

// LN core given the row value already in-register
__device__ __forceinline__ float ln_from_val(float v, int d,
                                             const float* __restrict__ g, const float* __restrict__ bta,
                                             float* sh1, float* sh2) {
    float s = v, s2 = v * v;
    #pragma unroll
    for (int o = 32; o >= 1; o >>= 1) { s += __shfl_down(s, o); s2 += __shfl_down(s2, o); }
    int lane = d & 63, w = d >> 6;
    if (lane == 0) { sh1[w] = s; sh2[w] = s2; }
    __syncthreads();
    if (d == 0) {
        float a = sh1[0] + sh1[1] + sh1[2] + sh1[3];
        float c = sh2[0] + sh2[1] + sh2[2] + sh2[3];
        sh1[0] = a; sh2[0] = c;
    }
    __syncthreads();
    float mean = sh1[0] * (1.0f / D_);
    float var  = sh2[0] * (1.0f / D_) - mean * mean;
    float rstd = rsqrtf(var + 1e-5f);
    return (v - mean) * rstd * g[d] + bta[d];
}

// LN -> bf16 out
__global__ __launch_bounds__(256) void ln_kernel(const float* __restrict__ x,
                                                 unsigned short* __restrict__ y,
                                                 const float* __restrict__ g,
                                                 const float* __restrict__ bta) {
    __shared__ float sh1[4], sh2[4];
    const int row = blockIdx.x, d = threadIdx.x;
    float v = x[(size_t)row * D_ + d];
    y[(size_t)row * D_ + d] = f2bf(ln_from_val(v, d, g, bta, sh1, sh2));
}

// LN2 fused with +enc and node/edge split, bf16 out
__global__ __launch_bounds__(256) void ln2enc_kernel(const float* __restrict__ x,
                                                     const float* __restrict__ g,
                                                     const float* __restrict__ bta,
                                                     const float* __restrict__ node_enc,
                                                     const float* __restrict__ edge_enc,
                                                     unsigned short* __restrict__ nodes_f,
                                                     unsigned short* __restrict__ edges_f) {
    __shared__ float sh1[4], sh2[4];
    const int row = blockIdx.x, d = threadIdx.x;
    float v = x[(size_t)row * D_ + d];
    float val = ln_from_val(v, d, g, bta, sh1, sh2);
    int b = row / NE_, pos = row % NE_;
    if (pos < N_) {
        int rn = b * N_ + pos;
        nodes_f[(size_t)rn * D_ + d] = f2bf(val + node_enc[(size_t)rn * D_ + d]);
    } else {
        int re = b * E_ + (pos - N_);
        edges_f[(size_t)re * D_ + d] = f2bf(val + edge_enc[(size_t)re * D_ + d]);
    }
}

// fused: node-rows aggregate CSR softmax inline; edge-rows read new_edges;
// then ne += ls2*gat and lnbuf = LN3(ne), bf16
__global__ __launch_bounds__(256) void gatagg_ln_kernel(
    const float* __restrict__ vals, const float* __restrict__ pres,
    const int* __restrict__ csr_off, const int* __restrict__ csr_perm,
    const float* __restrict__ new_edges, const float* __restrict__ ls2l,
    const float* __restrict__ g, const float* __restrict__ bta,
    float* __restrict__ ne, unsigned short* __restrict__ lnb) {
    __shared__ float sh1[4], sh2[4];
    __shared__ float sms[8], sden[8];
    const int row = blockIdx.x, d = threadIdx.x;
    int b = row / NE_, pos = row % NE_;
    float gv;
    if (pos < N_) {            // block-uniform branch
        int n = b * N_ + pos;
        int s = csr_off[n], e2 = csr_off[n + 1];
        if (d < 8) {
            float mx = -INFINITY;
            for (int i = s; i < e2; ++i) mx = fmaxf(mx, pres[csr_perm[i] * H_ + d]);
            float sum = 0.f;
            for (int i = s; i < e2; ++i) sum += __expf(pres[csr_perm[i] * H_ + d] - mx);
            sms[d] = mx; sden[d] = sum;
        }
        __syncthreads();
        int h = d >> 5;
        float ms = sms[h];
        float rd = 1.0f / sden[h];
        float acc = 0.f;
        for (int i = s; i < e2; ++i) {
            int e = csr_perm[i];
            acc += vals[(size_t)e * D_ + d] * (__expf(pres[e * H_ + h] - ms) * rd);
        }
        gv = acc;
    } else {
        gv = new_edges[(size_t)(b * E_ + (pos - N_)) * D_ + d];
    }
    float v = ne[(size_t)row * D_ + d] + ls2l[d] * gv;
    ne[(size_t)row * D_ + d] = v;
    lnb[(size_t)row * D_ + d] = f2bf(ln_from_val(v, d, g, bta, sh1, sh2));
}

// ---------------- weight transpose+cast: W[K,N] f32 -> Wt[N,K] bf16 ----------------
// K/V weight tiles go to kvwT [L*512][256] (contiguous across layers for batched KV GEMM)
__global__ __launch_bounds__(256) void wtrans_kernel(
    const float* __restrict__ Wqkv, const float* __restrict__ Wo,
    const float* __restrict__ Wn1,  const float* __restrict__ Wn2,
    const float* __restrict__ We,   const float* __restrict__ Weo,
    const float* __restrict__ Wno,  const float* __restrict__ W1,
    const float* __restrict__ W2,   unsigned short* __restrict__ wT,
    unsigned short* __restrict__ kvwT)
{
    const int bid = blockIdx.x;
    const int l = bid / 1088;
    int tl = bid % 1088;
    const float* src; int ld, K, Nn; unsigned short* dst;
    if (tl < 576) {
        int mid = tl >> 6; tl &= 63;
        K = 256; Nn = 256;
        if (mid == 0) {
            src = Wqkv + (size_t)l * 256 * 768; ld = 768;
            dst = wT + (size_t)l * LAYER_W + OFF_Q;
        } else if (mid < 3) {
            src = Wqkv + (size_t)l * 256 * 768 + mid * 256; ld = 768;
            dst = kvwT + ((size_t)l * 512 + (size_t)(mid - 1) * 256) * 256;
        } else {
            const float* bases[6] = {Wo, Wn1, Wn2, We, Weo, Wno};
            src = bases[mid - 3] + (size_t)l * 65536; ld = 256;
            dst = wT + (size_t)l * LAYER_W + OFF_WO + (size_t)(mid - 3) * 65536;
        }
    } else if (tl < 832) {
        tl -= 576; K = 256; Nn = 1024;
        src = W1 + (size_t)l * 262144; ld = 1024;
        dst = wT + (size_t)l * LAYER_W + OFF_W1;
    } else {
        tl -= 832; K = 1024; Nn = 256;
        src = W2 + (size_t)l * 262144; ld = 256;
        dst = wT + (size_t)l * LAYER_W + OFF_W2;
    }
    const int ntn = Nn >> 5;
    const int k0 = (tl / ntn) << 5, n0 = (tl % ntn) << 5;
    __shared__ float ts[32][33];
    const int t = threadIdx.x;
    const int kl = t >> 5, nl = t & 31;
    #pragma unroll
    for (int rr = 0; rr < 4; ++rr)
        ts[kl + rr * 8][nl] = src[(size_t)(k0 + kl + rr * 8) * ld + n0 + nl];
    __syncthreads();
    const int onl = t >> 3, okl = (t & 7) << 2;
    ushort4 o;
    o.x = f2bf(ts[okl + 0][onl]); o.y = f2bf(ts[okl + 1][onl]);
    o.z = f2bf(ts[okl + 2][onl]); o.w = f2bf(ts[okl + 3][onl]);
    *(ushort4*)&dst[(size_t)(n0 + onl) * K + k0 + okl] = o;
}

// ---------------- 64-tile MFMA GEMM ----------------
// Linear LDS [64][64] with XOR swizzle: swizzled col (halves) = col ^ ((row&7)<<3).

struct GArgs {
    const unsigned short* A;
    const unsigned short* Bt;
    const float* bias;
    const float* bias2;
    void* C;
    int lda, ldc, K, outbf, nbx;
};

template<int MODE, int OUTBF>
__global__ __launch_bounds__(256) void mgemm_kernel(
    const unsigned short* __restrict__ A, int lda,
    const unsigned short* __restrict__ Bt,
    const float* __restrict__ bias,
    const float* __restrict__ bias2,
    const float* __restrict__ res,
    const float* __restrict__ ls,
    void* __restrict__ Cv, int ldc, int K)
{
    __shared__ __align__(16) unsigned short As[64 * 64];
    __shared__ __align__(16) unsigned short Bs[64 * 64];
    const int m0 = blockIdx.y * 64, n0 = blockIdx.x * 64;
    const int t = threadIdx.x;
    const int l = t & 63, w = t >> 6;
    const int wr = (w >> 1) * 32, wc = (w & 1) * 32;
    const int frow = l & 15, kg = l >> 4;
    const int srow = w * 8 + (l >> 3);
    const int scolh = 8 * ((l & 7) ^ (l >> 3));
    const int ldsoff = w * 512;
    const int sw = (frow & 7) << 3;
    f32x4 acc[2][2];
    acc[0][0] = (f32x4){0.f,0.f,0.f,0.f}; acc[0][1] = acc[0][0];
    acc[1][0] = acc[0][0];                acc[1][1] = acc[0][0];
    for (int k0 = 0; k0 < K; k0 += 64) {
        const unsigned short* ga = A  + (size_t)(m0 + srow) * lda + k0 + scolh;
        const unsigned short* gb = Bt + (size_t)(n0 + srow) * K   + k0 + scolh;
        gload16(ga,                As + ldsoff);
        gload16(ga + 32 * lda,     As + ldsoff + 2048);
        gload16(gb,                Bs + ldsoff);
        gload16(gb + (size_t)32 * K, Bs + ldsoff + 2048);
        __syncthreads();
        #pragma unroll
        for (int kk = 0; kk < 2; ++kk) {
            const int off = (kk * 32 + kg * 8) ^ sw;
            bf16x8 af0 = *(const bf16x8*)&As[(wr + frow) * 64 + off];
            bf16x8 af1 = *(const bf16x8*)&As[(wr + 16 + frow) * 64 + off];
            bf16x8 bf0 = *(const bf16x8*)&Bs[(wc + frow) * 64 + off];
            bf16x8 bf1 = *(const bf16x8*)&Bs[(wc + 16 + frow) * 64 + off];
            acc[0][0] = __builtin_amdgcn_mfma_f32_16x16x32_bf16(af0, bf0, acc[0][0], 0, 0, 0);
            acc[0][1] = __builtin_amdgcn_mfma_f32_16x16x32_bf16(af0, bf1, acc[0][1], 0, 0, 0);
            acc[1][0] = __builtin_amdgcn_mfma_f32_16x16x32_bf16(af1, bf0, acc[1][0], 0, 0, 0);
            acc[1][1] = __builtin_amdgcn_mfma_f32_16x16x32_bf16(af1, bf1, acc[1][1], 0, 0, 0);
        }
        __syncthreads();
    }
    #pragma unroll
    for (int fr = 0; fr < 2; ++fr) {
        #pragma unroll
        for (int fc = 0; fc < 2; ++fc) {
            int n = n0 + wc + fc * 16 + frow;
            float bv = (bias2 != nullptr && n >= 256) ? bias2[n - 256] : bias[n];
            float lv = (MODE == 2) ? ls[n] : 0.f;
            #pragma unroll
            for (int rg = 0; rg < 4; ++rg) {
                int m = m0 + wr + fr * 16 + kg * 4 + rg;
                float vv = acc[fr][fc][rg] + bv;
                if (MODE == 1) vv = gelu_f(vv);
                if (MODE == 2) vv = res[(size_t)m * ldc + n] + lv * vv;
                if (OUTBF) ((unsigned short*)Cv)[(size_t)m * ldc + n] = f2bf(vv);
                else       ((float*)Cv)[(size_t)m * ldc + n] = vv;
            }
        }
    }
}

// WEO GEMM with fused vin epilogue
__global__ __launch_bounds__(256) void mgemm_weo_kernel(
    const unsigned short* __restrict__ A,
    const unsigned short* __restrict__ Bt,
    const float* __restrict__ bias,
    const unsigned short* __restrict__ nodes_f,
    const int* __restrict__ idx1,
    float* __restrict__ new_edges,
    unsigned short* __restrict__ vin)
{
    __shared__ __align__(16) unsigned short As[64 * 64];
    __shared__ __align__(16) unsigned short Bs[64 * 64];
    const int m0 = blockIdx.y * 64, n0 = blockIdx.x * 64;
    const int t = threadIdx.x;
    const int l = t & 63, w = t >> 6;
    const int wr = (w >> 1) * 32, wc = (w & 1) * 32;
    const int frow = l & 15, kg = l >> 4;
    const int srow = w * 8 + (l >> 3);
    const int scolh = 8 * ((l & 7) ^ (l >> 3));
    const int ldsoff = w * 512;
    const int sw = (frow & 7) << 3;
    f32x4 acc[2][2];
    acc[0][0] = (f32x4){0.f,0.f,0.f,0.f}; acc[0][1] = acc[0][0];
    acc[1][0] = acc[0][0];                acc[1][1] = acc[0][0];
    for (int k0 = 0; k0 < 256; k0 += 64) {
        const unsigned short* ga = A  + (size_t)(m0 + srow) * 256 + k0 + scolh;
        const unsigned short* gb = Bt + (size_t)(n0 + srow) * 256 + k0 + scolh;
        gload16(ga,                 As + ldsoff);
        gload16(ga + 32 * 256,      As + ldsoff + 2048);
        gload16(gb,                 Bs + ldsoff);
        gload16(gb + 32 * 256,      Bs + ldsoff + 2048);
        __syncthreads();
        #pragma unroll
        for (int kk = 0; kk < 2; ++kk) {
            const int off = (kk * 32 + kg * 8) ^ sw;
            bf16x8 af0 = *(const bf16x8*)&As[(wr + frow) * 64 + off];
            bf16x8 af1 = *(const bf16x8*)&As[(wr + 16 + frow) * 64 + off];
            bf16x8 bf0 = *(const bf16x8*)&Bs[(wc + frow) * 64 + off];
            bf16x8 bf1 = *(const bf16x8*)&Bs[(wc + 16 + frow) * 64 + off];
            acc[0][0] = __builtin_amdgcn_mfma_f32_16x16x32_bf16(af0, bf0, acc[0][0], 0, 0, 0);
            acc[0][1] = __builtin_amdgcn_mfma_f32_16x16x32_bf16(af0, bf1, acc[0][1], 0, 0, 0);
            acc[1][0] = __builtin_amdgcn_mfma_f32_16x16x32_bf16(af1, bf0, acc[1][0], 0, 0, 0);
            acc[1][1] = __builtin_amdgcn_mfma_f32_16x16x32_bf16(af1, bf1, acc[1][1], 0, 0, 0);
        }
        __syncthreads();
    }
    #pragma unroll
    for (int fr = 0; fr < 2; ++fr) {
        #pragma unroll
        for (int rg = 0; rg < 4; ++rg) {
            int m = m0 + wr + fr * 16 + kg * 4 + rg;
            int src = idx1[m];
            #pragma unroll
            for (int fc = 0; fc < 2; ++fc) {
                int n = n0 + wc + fc * 16 + frow;
                float vv = acc[fr][fc][rg] + bias[n];
                new_edges[(size_t)m * 256 + n] = vv;
                vin[(size_t)m * 256 + n] = f2bf(bf2f(nodes_f[(size_t)src * 256 + n]) + vv);
            }
        }
    }
}

// dual-descriptor GEMM: two independent MODE-0 GEMMs in one dispatch
__global__ __launch_bounds__(256) void mgemm2_kernel(GArgs g0, GArgs g1, int nblk0) {
    const bool first = (int)blockIdx.x < nblk0;
    GArgs g = first ? g0 : g1;
    const int bid = first ? blockIdx.x : blockIdx.x - nblk0;
    __shared__ __align__(16) unsigned short As[64 * 64];
    __shared__ __align__(16) unsigned short Bs[64 * 64];
    const int m0 = (bid / g.nbx) * 64, n0 = (bid % g.nbx) * 64;
    const int t = threadIdx.x;
    const int l = t & 63, w = t >> 6;
    const int wr = (w >> 1) * 32, wc = (w & 1) * 32;
    const int frow = l & 15, kg = l >> 4;
    const int srow = w * 8 + (l >> 3);
    const int scolh = 8 * ((l & 7) ^ (l >> 3));
    const int ldsoff = w * 512;
    const int sw = (frow & 7) << 3;
    f32x4 acc[2][2];
    acc[0][0] = (f32x4){0.f,0.f,0.f,0.f}; acc[0][1] = acc[0][0];
    acc[1][0] = acc[0][0];                acc[1][1] = acc[0][0];
    for (int k0 = 0; k0 < g.K; k0 += 64) {
        const unsigned short* ga = g.A  + (size_t)(m0 + srow) * g.lda + k0 + scolh;
        const unsigned short* gb = g.Bt + (size_t)(n0 + srow) * g.K   + k0 + scolh;
        gload16(ga,                  As + ldsoff);
        gload16(ga + 32 * g.lda,     As + ldsoff + 2048);
        gload16(gb,                  Bs + ldsoff);
        gload16(gb + (size_t)32 * g.K, Bs + ldsoff + 2048);
        __syncthreads();
        #pragma unroll
        for (int kk = 0; kk < 2; ++kk) {
            const int off = (kk * 32 + kg * 8) ^ sw;
            bf16x8 af0 = *(const bf16x8*)&As[(wr + frow) * 64 + off];
            bf16x8 af1 = *(const bf16x8*)&As[(wr + 16 + frow) * 64 + off];
            bf16x8 bf0 = *(const bf16x8*)&Bs[(wc + frow) * 64 + off];
            bf16x8 bf1 = *(const bf16x8*)&Bs[(wc + 16 + frow) * 64 + off];
            acc[0][0] = __builtin_amdgcn_mfma_f32_16x16x32_bf16(af0, bf0, acc[0][0], 0, 0, 0);
            acc[0][1] = __builtin_amdgcn_mfma_f32_16x16x32_bf16(af0, bf1, acc[0][1], 0, 0, 0);
            acc[1][0] = __builtin_amdgcn_mfma_f32_16x16x32_bf16(af1, bf0, acc[1][0], 0, 0, 0);
            acc[1][1] = __builtin_amdgcn_mfma_f32_16x16x32_bf16(af1, bf1, acc[1][1], 0, 0, 0);
        }
        __syncthreads();
    }
    #pragma unroll
    for (int fr = 0; fr < 2; ++fr) {
        #pragma unroll
        for (int fc = 0; fc < 2; ++fc) {
            int n = n0 + wc + fc * 16 + frow;
            float bv = (g.bias2 != nullptr && n >= 256) ? g.bias2[n - 256] : g.bias[n];
            #pragma unroll
            for (int rg = 0; rg < 4; ++rg) {
                int m = m0 + wr + fr * 16 + kg * 4 + rg;
                float vv = acc[fr][fc][rg] + bv;
                if (g.outbf) ((unsigned short*)g.C)[(size_t)m * g.ldc + n] = f2bf(vv);
                else         ((float*)g.C)[(size_t)m * g.ldc + n] = vv;
            }
        }
    }
}

// ---------------- 128-tile MFMA GEMM: generic (MODE 0/1) ----------------
template<int MODE>
__global__ __launch_bounds__(256) void mgemm128_kernel(
    const unsigned short* __restrict__ A, int lda,
    const unsigned short* __restrict__ Bt,
    const float* __restrict__ bias,
    unsigned short* __restrict__ C, int ldc, int K, int nbx)
{
    __shared__ __align__(16) unsigned short As[128 * 64];
    __shared__ __align__(16) unsigned short Bs[128 * 64];
    const int bid = blockIdx.x;
    const int m0 = (bid / nbx) * 128, n0 = (bid % nbx) * 128;
    const int t = threadIdx.x;
    const int l = t & 63, w = t >> 6;
    const int wr = (w >> 1) * 64, wc = (w & 1) * 64;
    const int frow = l & 15, kg = l >> 4;
    const int srow = w * 8 + (l >> 3);
    const int scolh = 8 * ((l & 7) ^ (l >> 3));
    const int ldsoff = w * 512;
    const int sw = (frow & 7) << 3;
    f32x4 acc[4][4];
    #pragma unroll
    for (int i = 0; i < 4; ++i)
        #pragma unroll
        for (int j = 0; j < 4; ++j) acc[i][j] = (f32x4){0.f, 0.f, 0.f, 0.f};
    for (int k0 = 0; k0 < K; k0 += 64) {
        #pragma unroll
        for (int j = 0; j < 4; ++j) {
            gload16(A  + (size_t)(m0 + j * 32 + srow) * lda + k0 + scolh, As + j * 2048 + ldsoff);
            gload16(Bt + (size_t)(n0 + j * 32 + srow) * K   + k0 + scolh, Bs + j * 2048 + ldsoff);
        }
        __syncthreads();
        #pragma unroll
        for (int kk = 0; kk < 2; ++kk) {
            const int off = (kk * 32 + kg * 8) ^ sw;
            bf16x8 af[4], bf[4];
            #pragma unroll
            for (int i = 0; i < 4; ++i) {
                af[i] = *(const bf16x8*)&As[(wr + i * 16 + frow) * 64 + off];
                bf[i] = *(const bf16x8*)&Bs[(wc + i * 16 + frow) * 64 + off];
            }
            #pragma unroll
            for (int i = 0; i < 4; ++i)
                #pragma unroll
                for (int j = 0; j < 4; ++j)
                    acc[i][j] = __builtin_amdgcn_mfma_f32_16x16x32_bf16(af[i], bf[j], acc[i][j], 0, 0, 0);
        }
        __syncthreads();
    }
    #pragma unroll
    for (int fr = 0; fr < 4; ++fr) {
        #pragma unroll
        for (int fc = 0; fc < 4; ++fc) {
            int n = n0 + wc + fc * 16 + frow;
            float bv = bias[n];
            #pragma unroll
            for (int rg = 0; rg < 4; ++rg) {
                int m = m0 + wr + fr * 16 + kg * 4 + rg;
                float vv = acc[fr][fc][rg] + bv;
                if (MODE == 1) vv = gelu_f(vv);
                C[(size_t)m * ldc + n] = f2bf(vv);
            }
        }
    }
}

// ---------------- batched all-layer K/V projection (128-tile, fused f32->bf16 A-cast) ----------------
// A staged from f32 `images` via reg+swizzled ds_write (read-matching XOR swizzle).
// Output remapped to per-layer contiguous [B*HW][512] buffers (layer = n>>9).
__global__ __launch_bounds__(256) void mgemmkv_kernel(
    const float* __restrict__ img,
    const unsigned short* __restrict__ kvwT,
    const float* __restrict__ bqkv,
    unsigned short* __restrict__ kvall)
{
    __shared__ __align__(16) unsigned short As[128 * 64];
    __shared__ __align__(16) unsigned short Bs[128 * 64];
    const int bid = blockIdx.x;
    const int m0 = (bid / 16) * 128, n0 = (bid % 16) * 128;
    const int t = threadIdx.x;
    const int l = t & 63, w = t >> 6;
    const int wr = (w >> 1) * 64, wc = (w & 1) * 64;
    const int frow = l & 15, kg = l >> 4;
    const int srow = w * 8 + (l >> 3);
    const int scolh = 8 * ((l & 7) ^ (l >> 3));
    const int ldsoff = w * 512;
    const int sw = (frow & 7) << 3;
    f32x4 acc[4][4];
    #pragma unroll
    for (int i = 0; i < 4; ++i)
        #pragma unroll
        for (int j = 0; j < 4; ++j) acc[i][j] = (f32x4){0.f, 0.f, 0.f, 0.f};
    for (int k0 = 0; k0 < 256; k0 += 64) {
        // B: linear-dest global_load_lds with inverse-swizzled source
        #pragma unroll
        for (int j = 0; j < 4; ++j)
            gload16(kvwT + (size_t)(n0 + j * 32 + srow) * 256 + k0 + scolh, Bs + j * 2048 + ldsoff);
        // A: f32 load -> bf16 pack -> ds_write at READ-swizzled offset
        #pragma unroll
        for (int i = 0; i < 4; ++i) {
            int u = t + i * 256;                   // 1024 uint4 slots for [128][64]
            int row = u >> 3, colh = (u & 7) * 8;
            const float* src = img + (size_t)(m0 + row) * 256 + k0 + colh;
            float4 a0 = *(const float4*)(src);
            float4 a1 = *(const float4*)(src + 4);
            int scol = colh ^ ((row & 7) * 8);
            *(uint4*)&As[row * 64 + scol] = make_uint4(pack2bf(a0.x, a0.y), pack2bf(a0.z, a0.w),
                                                       pack2bf(a1.x, a1.y), pack2bf(a1.z, a1.w));
        }
        __syncthreads();
        #pragma unroll
        for (int kk = 0; kk < 2; ++kk) {
            const int off = (kk * 32 + kg * 8) ^ sw;
            bf16x8 af[4], bf[4];
            #pragma unroll
            for (int i = 0; i < 4; ++i) {
                af[i] = *(const bf16x8*)&As[(wr + i * 16 + frow) * 64 + off];
                bf[i] = *(const bf16x8*)&Bs[(wc + i * 16 + frow) * 64 + off];
            }
            #pragma unroll
            for (int i = 0; i < 4; ++i)
                #pragma unroll
                for (int j = 0; j < 4; ++j)
                    acc[i][j] = __builtin_amdgcn_mfma_f32_16x16x32_bf16(af[i], bf[j], acc[i][j], 0, 0, 0);
        }
        __syncthreads();
    }
    #pragma unroll
    for (int fr = 0; fr < 4; ++fr) {
        #pragma unroll
        for (int fc = 0; fc < 4; ++fc) {
            int n = n0 + wc + fc * 16 + frow;
            int layer = n >> 9, nn = n & 511;
            float bv = bqkv[layer * 768 + 256 + nn];
            unsigned short* dst = kvall + (size_t)layer * KVSZ_ + nn;
            #pragma unroll
            for (int rg = 0; rg < 4; ++rg) {
                int m = m0 + wr + fr * 16 + kg * 4 + rg;
                dst[(size_t)m * 512] = f2bf(acc[fr][fc][rg] + bv);
            }
        }
    }
}

// ---------------- MFMA flash attention with fused Q-projection ----------------
// 1152 blocks x 128 threads. Block = one (b,h) x 32 q-rows (2 waves x 16 rows).
// Prologue: Q = lnbuf x Wq_head^T, staged in TWO K=128 passes ([32][136] tiles,
// 17.4 KB scratch -- fits within the Ks+Vs LDS region; no OOB).
__global__ __launch_bounds__(128) void attn_kernel(
    const unsigned short* __restrict__ lnb, const unsigned short* __restrict__ wq,
    const float* __restrict__ bqkv_l,
    const unsigned short* __restrict__ kv,
    const unsigned short* __restrict__ pmask, const int* __restrict__ maskflag,
    unsigned short* __restrict__ ctx)
{
    const int bid = blockIdx.x;
    const int h = bid & 7;
    const int qt = (bid >> 3) % 9;
    const int b = (bid >> 3) / 9;
    const int q0 = qt * 32;
    const int t = threadIdx.x;
    const int w = t >> 6, l = t & 63;
    const int lr = l & 15, lg = l >> 4;
    const int hasmask = *maskflag;

    __shared__ unsigned short Ks[2][64][40];     // 10240 B  (also prologue scratch start)
    __shared__ unsigned short Vs[2][32][72];     //  9216 B
    __shared__ unsigned short Pl[2][16][72];     //  4608 B
    __shared__ unsigned short Qlds[2][16][40];   //  2560 B

    // staging assignment (main loop)
    const int kkey = t >> 1, kdh = (t & 1) * 16;          // K: 1 key, 16 dh
    const int vdh = (t & 7) * 4, vk0 = (t >> 3) * 2;      // V: key pairs, 4 dh
    const unsigned short* kbase = kv + ((size_t)b * HW_) * 512 + h * DH_;
    const unsigned short* vbase = kv + ((size_t)b * HW_) * 512 + 256 + h * DH_;
    const uint4* mbase = (const uint4*)(pmask + (size_t)bid * NC_ * 2048 + t * 16);

    uint4 kq0, kq1;
    ushort4 va[2], vb4[2];
    uint4 mc0 = make_uint4(0,0,0,0), mc1 = mc0, mn0 = mc0, mn1 = mc0;

    auto issue_kv = [&](int c0) {
        {
            int key = c0 + kkey;
            bool ok = key < HW_;
            const unsigned short* kp = kbase + (size_t)(ok ? key : 0) * 512 + kdh;
            kq0 = *(const uint4*)(kp);
            kq1 = *(const uint4*)(kp + 8);
            if (!ok) { kq0 = make_uint4(0,0,0,0); kq1 = kq0; }
        }
        #pragma unroll
        for (int r = 0; r < 2; ++r) {
            int key = c0 + vk0 + 32 * r;
            bool ok0 = key < HW_, ok1 = (key + 1) < HW_;
            const unsigned short* vp = vbase + (size_t)(ok0 ? key : 0) * 512 + vdh;
            va[r]  = *(const ushort4*)(vp);
            vb4[r] = *(const ushort4*)(vp + (ok1 ? 512 : 0));
            if (!ok0) va[r]  = make_ushort4(0,0,0,0);
            if (!ok1) vb4[r] = make_ushort4(0,0,0,0);
        }
    };
    auto write_kv = [&](int bufi) {
        *(uint4*)&Ks[bufi][kkey][kdh]     = kq0;
        *(uint4*)&Ks[bufi][kkey][kdh + 8] = kq1;
        #pragma unroll
        for (int r = 0; r < 2; ++r) {
            const unsigned short* a = (const unsigned short*)&va[r];
            const unsigned short* c = (const unsigned short*)&vb4[r];
            #pragma unroll
            for (int i = 0; i < 4; ++i)
                *(unsigned*)&Vs[bufi][vdh + i][vk0 + 32 * r] = (unsigned)a[i] | ((unsigned)c[i] << 16);
        }
    };

    // issue chunk-0 K/V global loads early (registers only; hides latency under prologue)
    issue_kv(0);
    if (hasmask) { mc0 = mbase[0]; mc1 = mbase[1]; }

    // ---- Q-projection prologue (two K=128 passes; 17408 B scratch < Ks+Vs=19456 B) ----
    bf16x8 qfrag;
    {
        unsigned short* Aln = &Ks[0][0][0];            // [32][136]
        unsigned short* Wqs = Aln + 32 * 136;          // [32][136]
        const unsigned short* asrc = lnb + (size_t)(b * NE_ + q0) * 256;
        const unsigned short* wsrc = wq + (size_t)(h * DH_) * 256;
        f32x4 qa[2];
        qa[0] = (f32x4){0.f, 0.f, 0.f, 0.f}; qa[1] = qa[0];
        #pragma unroll
        for (int ph = 0; ph < 2; ++ph) {
            #pragma unroll
            for (int i = 0; i < 4; ++i) {
                int u = t + i * 128;                   // 512 uint4 per tile
                int row = u >> 4, col = (u & 15) * 8;
                *(uint4*)&Aln[row * 136 + col] = *(const uint4*)&asrc[(size_t)row * 256 + ph * 128 + col];
                *(uint4*)&Wqs[row * 136 + col] = *(const uint4*)&wsrc[(size_t)row * 256 + ph * 128 + col];
            }
            __syncthreads();
            #pragma unroll
            for (int kk = 0; kk < 4; ++kk) {
                bf16x8 af = *(const bf16x8*)&Aln[(w * 16 + lr) * 136 + kk * 32 + lg * 8];
                #pragma unroll
                for (int fc = 0; fc < 2; ++fc) {
                    bf16x8 bf = *(const bf16x8*)&Wqs[(fc * 16 + lr) * 136 + kk * 32 + lg * 8];
                    qa[fc] = __builtin_amdgcn_mfma_f32_16x16x32_bf16(af, bf, qa[fc], 0, 0, 0);
                }
            }
            __syncthreads();
        }
        #pragma unroll
        for (int fc = 0; fc < 2; ++fc) {
            float bq = bqkv_l[h * DH_ + fc * 16 + lr];
            #pragma unroll
            for (int rg = 0; rg < 4; ++rg)
                Qlds[w][lg * 4 + rg][fc * 16 + lr] = f2bf(qa[fc][rg] + bq);
        }
        __syncthreads();
        qfrag = *(const bf16x8*)&Qlds[w][lr][lg * 8];
    }

    f32x4 oacc[2];
    oacc[0] = (f32x4){0.f, 0.f, 0.f, 0.f}; oacc[1] = oacc[0];
    float m_i[4] = {-INFINITY, -INFINITY, -INFINITY, -INFINITY};
    float l_i[4] = {0.f, 0.f, 0.f, 0.f};

    write_kv(0);
    if (hasmask) { mn0 = mbase[128]; mn1 = mbase[129]; }
    __syncthreads();

    for (int c = 0; c < NC_; ++c) {
        const int c0 = c * 64;
        const int cb = c & 1, nb = cb ^ 1;
        if (c + 1 < NC_) issue_kv(c0 + 64);

        // QK^T: S[16 q, 64 keys]
        f32x4 sacc[4];
        #pragma unroll
        for (int fc = 0; fc < 4; ++fc) {
            sacc[fc] = (f32x4){0.f, 0.f, 0.f, 0.f};
            bf16x8 kf = *(const bf16x8*)&Ks[cb][fc * 16 + lr][lg * 8];
            sacc[fc] = __builtin_amdgcn_mfma_f32_16x16x32_bf16(qfrag, kf, sacc[fc], 0, 0, 0);
        }
        float s[4][4];   // [fc][rg]
        if (hasmask) {
            unsigned uw[8] = {mc0.x, mc0.y, mc0.z, mc0.w, mc1.x, mc1.y, mc1.z, mc1.w};
            #pragma unroll
            for (int rg = 0; rg < 4; ++rg) {
                s[0][rg] = sacc[0][rg] * SCALE_ + bf2f((unsigned short)(uw[rg * 2] & 0xffff));
                s[1][rg] = sacc[1][rg] * SCALE_ + bf2f((unsigned short)(uw[rg * 2] >> 16));
                s[2][rg] = sacc[2][rg] * SCALE_ + bf2f((unsigned short)(uw[rg * 2 + 1] & 0xffff));
                s[3][rg] = sacc[3][rg] * SCALE_ + bf2f((unsigned short)(uw[rg * 2 + 1] >> 16));
            }
            float mloc[4];
            #pragma unroll
            for (int rg = 0; rg < 4; ++rg)
                mloc[rg] = fmaxf(fmaxf(s[0][rg], s[1][rg]), fmaxf(s[2][rg], s[3][rg]));
            #pragma unroll
            for (int off = 1; off < 16; off <<= 1)
                #pragma unroll
                for (int rg = 0; rg < 4; ++rg)
                    mloc[rg] = fmaxf(mloc[rg], __shfl_xor(mloc[rg], off));
            float scl[4], lloc[4];
            #pragma unroll
            for (int rg = 0; rg < 4; ++rg) {
                float mn = fmaxf(m_i[rg], mloc[rg]);
                scl[rg] = __expf(m_i[rg] - mn);
                m_i[rg] = mn;
            }
            #pragma unroll
            for (int rg = 0; rg < 4; ++rg) {
                float acc = 0.f;
                #pragma unroll
                for (int fc = 0; fc < 4; ++fc) {
                    float p = __expf(s[fc][rg] - m_i[rg]);
                    s[fc][rg] = p;
                    acc += p;
                }
                lloc[rg] = acc;
            }
            #pragma unroll
            for (int off = 1; off < 16; off <<= 1)
                #pragma unroll
                for (int rg = 0; rg < 4; ++rg)
                    lloc[rg] += __shfl_xor(lloc[rg], off);
            #pragma unroll
            for (int rg = 0; rg < 4; ++rg) {
                l_i[rg] = l_i[rg] * scl[rg] + lloc[rg];
                oacc[0][rg] *= scl[rg];
                oacc[1][rg] *= scl[rg];
            }
        } else {
            // fixed-max softmax (scores bounded << 88): no max tracking
            const bool tailc = (c == NC_ - 1);
            float lloc[4] = {0.f, 0.f, 0.f, 0.f};
            #pragma unroll
            for (int fc = 0; fc < 4; ++fc) {
                float pad = (tailc && (c0 + fc * 16 + lr) >= HW_) ? -1e30f : 0.f;
                #pragma unroll
                for (int rg = 0; rg < 4; ++rg) {
                    float p = __expf(sacc[fc][rg] * SCALE_ + pad);
                    s[fc][rg] = p;
                    lloc[rg] += p;
                }
            }
            #pragma unroll
            for (int off = 1; off < 16; off <<= 1)
                #pragma unroll
                for (int rg = 0; rg < 4; ++rg)
                    lloc[rg] += __shfl_xor(lloc[rg], off);
            #pragma unroll
            for (int rg = 0; rg < 4; ++rg)
                l_i[rg] += lloc[rg];
        }

        // P -> LDS (wave-private), then PV
        #pragma unroll
        for (int fc = 0; fc < 4; ++fc)
            #pragma unroll
            for (int rg = 0; rg < 4; ++rg)
                Pl[w][lg * 4 + rg][fc * 16 + lr] = f2bf(s[fc][rg]);
        #pragma unroll
        for (int ks2 = 0; ks2 < 2; ++ks2) {
            bf16x8 pf = *(const bf16x8*)&Pl[w][lr][ks2 * 32 + lg * 8];
            #pragma unroll
            for (int d2 = 0; d2 < 2; ++d2) {
                bf16x8 vf = *(const bf16x8*)&Vs[cb][d2 * 16 + lr][ks2 * 32 + lg * 8];
                oacc[d2] = __builtin_amdgcn_mfma_f32_16x16x32_bf16(pf, vf, oacc[d2], 0, 0, 0);
            }
        }

        if (hasmask) {
            mc0 = mn0; mc1 = mn1;
            if (c + 2 < NC_) {
                mn0 = mbase[(c + 2) * 128];
                mn1 = mbase[(c + 2) * 128 + 1];
            }
        }
        if (c + 1 < NC_) {
            write_kv(nb);
            __syncthreads();
        }
    }

    unsigned short* cbase = ctx + ((size_t)(b * NE_ + q0 + w * 16 + lg * 4)) * D_ + h * DH_;
    #pragma unroll
    for (int rg = 0; rg < 4; ++rg) {
        float inv = 1.0f / l_i[rg];
        #pragma unroll
        for (int d2 = 0; d2 < 2; ++d2)
            cbase[(size_t)rg * D_ + d2 * 16 + lr] = f2bf(oacc[d2][rg] * inv);
    }
}

// ---------------- GAT kernels ----------------

__global__ __launch_bounds__(256) void hidden_kernel(
    const float* __restrict__ gn12,
    unsigned short* __restrict__ hid, const int* __restrict__ idx0,
    const float* __restrict__ attn_p_l, float* __restrict__ pres) {
    int e = blockIdx.x;
    int d = threadIdx.x;
    int n = idx0[e];
    float x = bf2f(hid[(size_t)e * D_ + d]) + gn12[(size_t)n * 512 + d] + gn12[(size_t)n * 512 + 256 + d];
    float hv = gelu_f(x);
    hid[(size_t)e * D_ + d] = f2bf(hv);
    float pr = hv * attn_p_l[d];
    #pragma unroll
    for (int o = 1; o < 32; o <<= 1) pr += __shfl_xor(pr, o);
    if ((d & 31) == 0) pres[e * H_ + (d >> 5)] = pr;
}

// ---------------- CSR build (deterministic) ----------------

__global__ __launch_bounds__(512) void csr_build_kernel(const int* __restrict__ idx0,
                                                        int* __restrict__ csr_off) {
    __shared__ int cnt[BN_];
    __shared__ int buf[BN_];
    int t = threadIdx.x;
    cnt[t] = 0;
    __syncthreads();
    #pragma unroll
    for (int i = 0; i < BE_ / 512; ++i)
        atomicAdd(&cnt[idx0[t + i * 512]], 1);
    __syncthreads();
    int c = cnt[t];
    buf[t] = c;
    __syncthreads();
    for (int o = 1; o < BN_; o <<= 1) {
        int add = (t >= o) ? buf[t - o] : 0;
        __syncthreads();
        buf[t] += add;
        __syncthreads();
    }
    csr_off[t] = buf[t] - c;
    if (t == BN_ - 1) csr_off[BN_] = buf[t];
}

__global__ __launch_bounds__(64) void csr_fill(const int* __restrict__ idx0,
                                               const int* __restrict__ csr_off,
                                               int* __restrict__ csr_perm) {
    int n = blockIdx.x;
    int lane = threadIdx.x;
    int w = csr_off[n];
    for (int c0 = 0; c0 < BE_; c0 += 64) {
        int e = c0 + lane;
        bool m = (idx0[e] == n);
        unsigned long long bal = __ballot(m);
        if (m) {
            int pre = __popcll(bal & ((1ull << lane) - 1ull));
            csr_perm[w + pre] = e;
        }
        w += __popcll(bal);
    }
}

// ---------------- host orchestration ----------------

static void launch_mgemm(hipStream_t s, int mode, int outbf,
                         const unsigned short* A, int lda, const unsigned short* Bt,
                         const float* bias, const float* bias2, const float* res, const float* ls,
                         void* C, int ldc, int M, int N, int K) {
    dim3 g(N / 64, M / 64);
    if (mode == 0) {
        if (outbf) mgemm_kernel<0,1><<<g, 256, 0, s>>>(A, lda, Bt, bias, bias2, res, ls, C, ldc, K);
        else       mgemm_kernel<0,0><<<g, 256, 0, s>>>(A, lda, Bt, bias, bias2, res, ls, C, ldc, K);
    } else if (mode == 1) {
        mgemm_kernel<1,1><<<g, 256, 0, s>>>(A, lda, Bt, bias, bias2, res, ls, C, ldc, K);
    } else {
        mgemm_kernel<2,0><<<g, 256, 0, s>>>(A, lda, Bt, bias, bias2, res, ls, C, ldc, K);
    }
}

extern "C" void kernel_launch(void* const* d_in, const int* in_sizes, int n_in,
                              void* d_out, int out_size, void* d_ws, size_t ws_size,
                              hipStream_t stream) {
    const float* nodes    = (const float*)d_in[0];
    const float* edges    = (const float*)d_in[1];
    const float* images   = (const float*)d_in[2];
    const float* mask     = (const float*)d_in[3];
    const float* node_enc = (const float*)d_in[4];
    const float* edge_enc = (const float*)d_in[5];
    const float* ln1_g = (const float*)d_in[6];
    const float* ln1_b = (const float*)d_in[7];
    const float* Wqkv  = (const float*)d_in[8];
    const float* bqkv  = (const float*)d_in[9];
    const float* Wo    = (const float*)d_in[10];
    const float* bo    = (const float*)d_in[11];
    const float* ls1   = (const float*)d_in[12];
    const float* ln2_g = (const float*)d_in[13];
    const float* ln2_b = (const float*)d_in[14];
    const float* Wn1   = (const float*)d_in[15];
    const float* bn1   = (const float*)d_in[16];
    const float* Wn2   = (const float*)d_in[17];
    const float* bn2   = (const float*)d_in[18];
    const float* We    = (const float*)d_in[19];
    const float* be    = (const float*)d_in[20];
    const float* attn_p= (const float*)d_in[21];
    const float* Weo   = (const float*)d_in[22];
    const float* beo   = (const float*)d_in[23];
    const float* Wno   = (const float*)d_in[24];
    const float* bno   = (const float*)d_in[25];
    const float* ls2   = (const float*)d_in[26];
    const float* ln3_g = (const float*)d_in[27];
    const float* ln3_b = (const float*)d_in[28];
    const float* W1    = (const float*)d_in[29];
    const float* b1    = (const float*)d_in[30];
    const float* W2    = (const float*)d_in[31];
    const float* b2    = (const float*)d_in[32];
    const float* ls3   = (const float*)d_in[33];
    const int*   edge_index = (const int*)d_in[34];
    const int* idx0 = edge_index;
    const int* idx1 = edge_index + BE_;

    float* ne = (float*)d_out;   // d_out doubles as the running `ne` buffer

    float* cur = (float*)d_ws;
    auto alloc = [&](size_t nfl) { float* p = cur; cur += nfl; return p; };
    auto allocbf = [&](size_t nbf) { float* p = cur; cur += (nbf + 1) / 2; return (unsigned short*)p; };

    unsigned short* lnbuf   = allocbf((size_t)B_ * NE_ * D_);
    unsigned short* kvall   = allocbf((size_t)L_ * KVSZ_);         // per-layer contiguous K|V
    unsigned short* ffnh    = allocbf((size_t)B_ * NE_ * FF_);
    unsigned short* ctxb    = allocbf((size_t)B_ * NE_ * D_);
    unsigned short* nodes_f = allocbf((size_t)BN_ * D_);
    unsigned short* edges_f = allocbf((size_t)BE_ * D_);
    unsigned short* hid     = allocbf((size_t)BE_ * D_);
    unsigned short* vin     = allocbf((size_t)BE_ * D_);
    unsigned short* pmaskb  = allocbf((size_t)NBLK_ * NC_ * 2048); // fragment-layout bf16 mask
    unsigned short* kvwT    = allocbf((size_t)L_ * 512 * 256);     // all-layer K/V weights^T
    float* gn12     = alloc((size_t)BN_ * 512);
    float* pres     = alloc((size_t)BE_ * H_);
    float* new_edges= alloc((size_t)BE_ * D_);
    float* valsb    = alloc((size_t)BE_ * D_);
    int* csr_off  = (int*)cur; cur += BN_ + 4;
    int* csr_perm = (int*)cur; cur += BE_;
    int* maskflag = (int*)cur; cur += 4;
    cur = (float*)(((uintptr_t)cur + 255) & ~(uintptr_t)255);
    unsigned short* wT = (unsigned short*)cur;   // 4 * LAYER_W bf16

    // ---- once-per-call preprocessing ----
    zeroinit_kernel<<<1, 64, 0, stream>>>(maskflag);
    maskchk_kernel<<<2048, 256, 0, stream>>>(mask, maskflag);
    wtrans_kernel<<<4 * 1088, 256, 0, stream>>>(Wqkv, Wo, Wn1, Wn2, We, Weo, Wno, W1, W2, wT, kvwT);
    premask_kernel<<<NBLK_ * NC_, 128, 0, stream>>>(mask, pmaskb, maskflag);
    csr_build_kernel<<<1, 512, 0, stream>>>(idx0, csr_off);
    csr_fill<<<BN_, 64, 0, stream>>>(idx0, csr_off, csr_perm);
    concat_kernel<<<(B_ * NE_ * D_) / 256, 256, 0, stream>>>(nodes, edges, ne);
    // batched all-layer K/V projection (f32 A-cast fused; per-layer contiguous output)
    mgemmkv_kernel<<<(B_ * HW_ / 128) * 16, 256, 0, stream>>>(images, kvwT, bqkv, kvall);

    for (int l = 0; l < L_; ++l) {
        const unsigned short* wTl = wT + (size_t)l * LAYER_W;
        const float* bqkv_l = bqkv + (size_t)l * 3 * D_;

        // ---- cross attention (Q-projection fused into attn) ----
        ln_kernel<<<B_ * NE_, 256, 0, stream>>>(ne, lnbuf, ln1_g + l * D_, ln1_b + l * D_);
        attn_kernel<<<NBLK_, 128, 0, stream>>>(lnbuf, wTl + OFF_Q, bqkv_l,
                                               kvall + (size_t)l * KVSZ_, pmaskb, maskflag, ctxb);
        launch_mgemm(stream, 2, 0, ctxb, D_, wTl + OFF_WO, bo + l * D_, nullptr, ne, ls1 + l * D_,
                     ne, D_, B_ * NE_, D_, D_);

        // ---- GAT ----
        ln2enc_kernel<<<B_ * NE_, 256, 0, stream>>>(ne, ln2_g + l * D_, ln2_b + l * D_,
                                                    node_enc, edge_enc, nodes_f, edges_f);
        {   // fused gn12 (nodes) + We (edges) in one dispatch
            GArgs gn { nodes_f, wTl + OFF_WN1, bn1 + l * D_, bn2 + l * D_, gn12, 256, 512, 256, 0, 8 };
            GArgs ge { edges_f, wTl + OFF_WE,  be + l * D_,  nullptr,      hid,  256, 256, 256, 1, 4 };
            int nb0 = (BN_ / 64) * 8;               // 64
            int nb1 = (BE_ / 64) * 4;               // 256
            mgemm2_kernel<<<nb0 + nb1, 256, 0, stream>>>(gn, ge, nb0);
        }
        hidden_kernel<<<BE_, 256, 0, stream>>>(gn12, hid, idx0, attn_p + (size_t)l * H_ * DH_, pres);
        mgemm_weo_kernel<<<dim3(4, BE_ / 64), 256, 0, stream>>>(
            hid, wTl + OFF_WEO, beo + l * D_, nodes_f, idx1, new_edges, vin);
        launch_mgemm(stream, 0, 0, vin, D_, wTl + OFF_WNO, bno + l * D_, nullptr, nullptr, nullptr,
                     valsb, D_, BE_, D_, D_);
        gatagg_ln_kernel<<<B_ * NE_, 256, 0, stream>>>(valsb, pres, csr_off, csr_perm,
                                                       new_edges, ls2 + l * D_,
                                                       ln3_g + l * D_, ln3_b + l * D_, ne, lnbuf);

        // ---- FFN ----
        mgemm128_kernel<1><<<(B_ * NE_ / 128) * (FF_ / 128), 256, 0, stream>>>(
            lnbuf, 256, wTl + OFF_W1, b1 + l * FF_, ffnh, FF_, 256, FF_ / 128);
        launch_mgemm(stream, 2, 0, ffnh, FF_, wTl + OFF_W2, b2 + l * D_, nullptr, ne, ls3 + l * D_,
                     ne, D_, B_ * NE_, D_, FF_);
    }
}